// Round 10
// baseline (458.219 us; speedup 1.0000x reference)
//
#include <hip/hip_runtime.h>
#include <hip/hip_bf16.h>

// Problem constants (fixed by reference)
#define BB 8
#define LL 4096
#define CC 552      // DIM
#define EE 1104     // EXP
#define KT 409      // top-k
#define M1 32768    // B*L
#define M2 3272     // B*KT
#define KP 576      // K padded (gemm over DIM)
#define KP2 1120    // K padded (gemm over EXP)
#define M2P 3328    // M2 padded to 26*128
#define JT 16       // SSM truncation taps (||A||^16 ~ 2e-13)
#define JC 19       // composed conv4 * ssm16 taps
#define NQT 5       // col tiles in gemmq (640/128)

typedef __attribute__((ext_vector_type(8))) short bf16x8;
typedef __attribute__((ext_vector_type(4))) float f32x4;

__device__ __forceinline__ ushort f2bf(float f) {
    unsigned u = __float_as_uint(f);
    return (ushort)((u + 0x7FFFu + ((u >> 16) & 1u)) >> 16);  // RNE
}
__device__ __forceinline__ float bf2f(ushort h) {
    return __uint_as_float(((unsigned)h) << 16);
}

// async global->LDS, 16B per lane; LDS dest = wave-uniform base + lane*16 [m97/m03]
__device__ __forceinline__ void gl_lds16(const ushort* g, ushort* l) {
    __builtin_amdgcn_global_load_lds(
        (const __attribute__((address_space(1))) void*)g,
        (__attribute__((address_space(3))) void*)l, 16, 0, 0);
}

// ---------- fused prep: qpart=0, posm=-1, winp/winpT ----------
__global__ void prep_kernel(const float* __restrict__ w_in, const float* __restrict__ norm_w,
                            float* __restrict__ winp, float* __restrict__ winpT,
                            float* __restrict__ qpart, int* __restrict__ posm) {
    int i = blockIdx.x * blockDim.x + threadIdx.x;
    if (i < NQT * M1) qpart[i] = 0.f;
    if (i < M1) posm[i] = -1;
    if (i < EE * CC) {
        int c = i % CC, e = i / CC;
        float v = w_in[i] * norm_w[c];
        winp[i] = v;
        winpT[(size_t)c * EE + e] = v;
    }
}

// ---------- convx: wave-per-row; bf16 hi/lo + inv + fp64 dval = <x_r, g_b> ----------
__global__ __launch_bounds__(256) void convx_kernel(const float* __restrict__ x,
                                                    const double* __restrict__ gbuf,
                                                    ushort* __restrict__ xh, ushort* __restrict__ xl,
                                                    float* __restrict__ inv,
                                                    double* __restrict__ dval) {
    const int wave = threadIdx.x >> 6, lane = threadIdx.x & 63;
    const int r = blockIdx.x * 4 + wave;
    const int b = r >> 12;
    const float* xr = x + (size_t)r * CC;
    const double* gb = gbuf + (size_t)b * CC;
    ushort* oh = xh + (size_t)r * KP;
    ushort* ol = xl + (size_t)r * KP;
    float ss = 0.f;
    double d = 0.0;
#pragma unroll
    for (int k = 0; k < 3; k++) {
        const int c = lane + k * 64;
        if (c < 144) {
            float4 v = make_float4(0.f, 0.f, 0.f, 0.f);
            if (c < 138) {
                v = reinterpret_cast<const float4*>(xr)[c];
                ss += v.x * v.x + v.y * v.y + v.z * v.z + v.w * v.w;
                const double* gp = gb + c * 4;
                d += (double)v.x * gp[0] + (double)v.y * gp[1] +
                     (double)v.z * gp[2] + (double)v.w * gp[3];
            }
            ushort4 h, l;
            h.x = f2bf(v.x); l.x = f2bf(v.x - bf2f(h.x));
            h.y = f2bf(v.y); l.y = f2bf(v.y - bf2f(h.y));
            h.z = f2bf(v.z); l.z = f2bf(v.z - bf2f(h.z));
            h.w = f2bf(v.w); l.w = f2bf(v.w - bf2f(h.w));
            reinterpret_cast<ushort4*>(oh)[c] = h;
            reinterpret_cast<ushort4*>(ol)[c] = l;
        }
    }
#pragma unroll
    for (int o = 32; o > 0; o >>= 1) { ss += __shfl_down(ss, o, 64); d += __shfl_down(d, o, 64); }
    if (lane == 0) {
        inv[r] = 1.f / (sqrtf(ss / (float)CC) + 1e-6f);
        dval[r] = d;
    }
}

// ---------- device bodies for fused weight conversions ----------
__device__ __forceinline__ void conv_row_kp(const float* __restrict__ src, int n, int nvalid,
                                            ushort* __restrict__ wh, ushort* __restrict__ wl, int t) {
    if (t >= 144) return;
    float4 v = make_float4(0.f, 0.f, 0.f, 0.f);
    if (n < nvalid && t < 138) v = reinterpret_cast<const float4*>(src + (size_t)n * CC)[t];
    ushort4 h, l;
    h.x = f2bf(v.x); l.x = f2bf(v.x - bf2f(h.x));
    h.y = f2bf(v.y); l.y = f2bf(v.y - bf2f(h.y));
    h.z = f2bf(v.z); l.z = f2bf(v.z - bf2f(h.z));
    h.w = f2bf(v.w); l.w = f2bf(v.w - bf2f(h.w));
    reinterpret_cast<ushort4*>(wh + (size_t)n * KP)[t] = h;
    reinterpret_cast<ushort4*>(wl + (size_t)n * KP)[t] = l;
}

__device__ __forceinline__ void conv_row_kp2(const float* __restrict__ src, int n,
                                             ushort* __restrict__ wh, ushort* __restrict__ wl, int t) {
    for (int i = t; i < KP2 / 4; i += 256) {
        float4 v = make_float4(0.f, 0.f, 0.f, 0.f);
        if (n < CC && i < EE / 4) v = reinterpret_cast<const float4*>(src + (size_t)n * EE)[i];
        ushort4 h, l;
        h.x = f2bf(v.x); l.x = f2bf(v.x - bf2f(h.x));
        h.y = f2bf(v.y); l.y = f2bf(v.y - bf2f(h.y));
        h.z = f2bf(v.z); l.z = f2bf(v.z - bf2f(h.z));
        h.w = f2bf(v.w); l.w = f2bf(v.w - bf2f(h.w));
        reinterpret_cast<ushort4*>(wh + (size_t)n * KP2)[i] = h;
        reinterpret_cast<ushort4*>(wl + (size_t)n * KP2)[i] = l;
    }
}

__device__ void taps19_body(const float* __restrict__ A, const float* __restrict__ Bp,
                            const float* __restrict__ Cp, const float* __restrict__ conv_w,
                            float* __restrict__ ck19, int t) {
    __shared__ float Ash[256];
    __shared__ float vmat[JT][16];
    Ash[t] = A[t];
    __syncthreads();
    if (t < 16) vmat[0][t] = 1.f / (1.f + expf(-Bp[t]));
    __syncthreads();
    for (int j = 1; j < JT; j++) {
        float nv = 0.f;
        if (t < 16) {
#pragma unroll
            for (int s2 = 0; s2 < 16; s2++) nv += Ash[t * 16 + s2] * vmat[j - 1][s2];
        }
        __syncthreads();
        if (t < 16) vmat[j][t] = nv;
        __syncthreads();
    }
    for (int e = t; e < EE; e += 256) {
        float sc[16];
#pragma unroll
        for (int s = 0; s < 16; s++) sc[s] = 1.f / (1.f + expf(-Cp[e * 16 + s]));
        float ck[JT];
#pragma unroll
        for (int j = 0; j < JT; j++) {
            float kk = 0.f;
#pragma unroll
            for (int s = 0; s < 16; s++) kk += sc[s] * vmat[j][s];
            ck[j] = kk;
        }
        float w4[4];
#pragma unroll
        for (int i = 0; i < 4; i++) w4[i] = conv_w[e * 4 + 3 - i];
#pragma unroll
        for (int m = 0; m < JC; m++) {
            float kk = 0.f;
#pragma unroll
            for (int i = 0; i < 4; i++) {
                int jm = m - i;
                if (jm >= 0 && jm < JT) kk += w4[i] * ck[jm];
            }
            ck19[m * EE + e] = kk;
        }
    }
}

// ---------- fused weight conversions + taps (independent roles by blockIdx) ----------
__global__ __launch_bounds__(256) void wconv_fused(
    const float* __restrict__ winp, const float* __restrict__ w_out,
    const float* __restrict__ winpT,
    const float* __restrict__ A, const float* __restrict__ Bp,
    const float* __restrict__ Cp, const float* __restrict__ conv_w,
    ushort* __restrict__ wh, ushort* __restrict__ wl,
    ushort* __restrict__ w2h, ushort* __restrict__ w2l,
    ushort* __restrict__ wth, ushort* __restrict__ wtl,
    float* __restrict__ ck19) {
    int bx = blockIdx.x;
    const int t = threadIdx.x;
    if (bx < 1152) { conv_row_kp(winp, bx, EE, wh, wl, t); return; }
    bx -= 1152;
    if (bx < 640) { conv_row_kp2(w_out, bx, w2h, w2l, t); return; }
    bx -= 640;
    if (bx < 640) { conv_row_kp2(winpT, bx, wth, wtl, t); return; }
    taps19_body(A, Bp, Cp, conv_w, ck19, t);
}

// ---------- triangular-masked conversion of G: Ghat[n][k] = G[n][k]*(n>k?2:n==k?1:0) ----------
__global__ __launch_bounds__(256) void convG_kernel(const float* __restrict__ G,
                                                    ushort* __restrict__ gh, ushort* __restrict__ gl) {
    const int n = blockIdx.x, t = threadIdx.x;
    if (t >= 144) return;
    float4 v = make_float4(0.f, 0.f, 0.f, 0.f);
    if (n < CC && t < 138) {
        v = reinterpret_cast<const float4*>(G + (size_t)n * CC)[t];
        const int k0 = t * 4;
        float m0 = (n > k0 + 0) ? 2.f : (n == k0 + 0) ? 1.f : 0.f;
        float m1 = (n > k0 + 1) ? 2.f : (n == k0 + 1) ? 1.f : 0.f;
        float m2 = (n > k0 + 2) ? 2.f : (n == k0 + 2) ? 1.f : 0.f;
        float m3 = (n > k0 + 3) ? 2.f : (n == k0 + 3) ? 1.f : 0.f;
        v = make_float4(v.x * m0, v.y * m1, v.z * m2, v.w * m3);
    }
    ushort4 h, l;
    h.x = f2bf(v.x); l.x = f2bf(v.x - bf2f(h.x));
    h.y = f2bf(v.y); l.y = f2bf(v.y - bf2f(h.y));
    h.z = f2bf(v.z); l.z = f2bf(v.z - bf2f(h.z));
    h.w = f2bf(v.w); l.w = f2bf(v.w - bf2f(h.w));
    reinterpret_cast<ushort4*>(gh + (size_t)n * KP)[t] = h;
    reinterpret_cast<ushort4*>(gl + (size_t)n * KP)[t] = l;
}

// ---------- unified split-bf16 MFMA GEMM, 2-phase prefetch (T3 minimum 2-phase) ----------
// C = rowscale[m]*(A@B^T) + bias[n]; operands pre-padded (128-row / 32-K multiples).
__global__ __launch_bounds__(256) void gemm_mfma(
    const ushort* __restrict__ Ah, const ushort* __restrict__ Al,   // [Mp][Kp]
    const ushort* __restrict__ Bh, const ushort* __restrict__ Bl,   // [Np][Kp]
    const float* __restrict__ rowscale, const float* __restrict__ bias,
    float* __restrict__ C, int ldc, int M, int N, int Kp, int r0) {
    __shared__ ushort As_h[2][128][32];
    __shared__ ushort As_l[2][128][32];
    __shared__ ushort Bs_h[2][128][32];
    __shared__ ushort Bs_l[2][128][32];
    const int tid = threadIdx.x;
    const int col0 = blockIdx.x * 128;
    const int row0 = blockIdx.y * 128;
    const int wave = tid >> 6, lane = tid & 63;
    const int wr = (wave >> 1) * 64, wc = (wave & 1) * 64;
    const int lrow = lane & 15, kb = (lane >> 4) * 8;

    const int s0 = wave * 32 + (lane >> 2);
    const int skh = (lane & 3) * 8;
    const ushort* gAh0 = Ah + (size_t)(row0 + s0) * Kp + skh;
    const ushort* gAl0 = Al + (size_t)(row0 + s0) * Kp + skh;
    const ushort* gBh0 = Bh + (size_t)(col0 + s0) * Kp + skh;
    const ushort* gBl0 = Bl + (size_t)(col0 + s0) * Kp + skh;
    const size_t rstep = (size_t)16 * Kp;

    f32x4 acc[4][4];
    const f32x4 zero = {0.f, 0.f, 0.f, 0.f};
#pragma unroll
    for (int i = 0; i < 4; i++)
#pragma unroll
        for (int j = 0; j < 4; j++) acc[i][j] = zero;

    auto stage = [&](int buf, int k0) {
        gl_lds16(gAh0 + k0, &As_h[buf][wave * 32][0]);
        gl_lds16(gAh0 + rstep + k0, &As_h[buf][wave * 32 + 16][0]);
        gl_lds16(gAl0 + k0, &As_l[buf][wave * 32][0]);
        gl_lds16(gAl0 + rstep + k0, &As_l[buf][wave * 32 + 16][0]);
        gl_lds16(gBh0 + k0, &Bs_h[buf][wave * 32][0]);
        gl_lds16(gBh0 + rstep + k0, &Bs_h[buf][wave * 32 + 16][0]);
        gl_lds16(gBl0 + k0, &Bs_l[buf][wave * 32][0]);
        gl_lds16(gBl0 + rstep + k0, &Bs_l[buf][wave * 32 + 16][0]);
    };
    auto compute = [&](int buf) {
        bf16x8 ah[4], al[4], bh[4], bl[4];
#pragma unroll
        for (int i = 0; i < 4; i++) {
            ah[i] = *reinterpret_cast<const bf16x8*>(&As_h[buf][wr + i * 16 + lrow][kb]);
            al[i] = *reinterpret_cast<const bf16x8*>(&As_l[buf][wr + i * 16 + lrow][kb]);
            bh[i] = *reinterpret_cast<const bf16x8*>(&Bs_h[buf][wc + i * 16 + lrow][kb]);
            bl[i] = *reinterpret_cast<const bf16x8*>(&Bs_l[buf][wc + i * 16 + lrow][kb]);
        }
#pragma unroll
        for (int i = 0; i < 4; i++)
#pragma unroll
            for (int j = 0; j < 4; j++) {
                acc[i][j] = __builtin_amdgcn_mfma_f32_16x16x32_bf16(ah[i], bh[j], acc[i][j], 0, 0, 0);
                acc[i][j] = __builtin_amdgcn_mfma_f32_16x16x32_bf16(ah[i], bl[j], acc[i][j], 0, 0, 0);
                acc[i][j] = __builtin_amdgcn_mfma_f32_16x16x32_bf16(al[i], bh[j], acc[i][j], 0, 0, 0);
            }
    };

    // 2-phase: prefetch next K-tile into buf^1 BEFORE computing buf; one barrier/step.
    stage(0, 0);
    __syncthreads();
    int cur = 0;
    for (int k0 = 32; k0 < Kp; k0 += 32) {
        stage(cur ^ 1, k0);   // loads fly while we compute below
        compute(cur);
        __syncthreads();      // compiler drains vmcnt+lgkmcnt here
        cur ^= 1;
    }
    compute(cur);

    // epilogue: C/D layout col=lane&15, row=(lane>>4)*4+reg  [m89-verified]
#pragma unroll
    for (int i = 0; i < 4; i++) {
        const int gmb = r0 + row0 + wr + i * 16 + (lane >> 4) * 4;
#pragma unroll
        for (int reg = 0; reg < 4; reg++) {
            const int gm = gmb + reg;
            if (gm < M) {
                const float rs = rowscale ? rowscale[gm] : 1.f;
#pragma unroll
                for (int j = 0; j < 4; j++) {
                    const int gn = col0 + wc + j * 16 + lrow;
                    if (gn < N) C[(size_t)gm * ldc + gn] = acc[i][j][reg] * rs + (bias ? bias[gn] : 0.f);
                }
            }
        }
    }
}

// ---------- gemmq: 128x128, 2-phase prefetch, fused q epilogue, triangular kend ----------
__global__ __launch_bounds__(256) void gemm_mfma_q(
    const ushort* __restrict__ Ah, const ushort* __restrict__ Al,   // x hi/lo [M1][KP]
    const ushort* __restrict__ Bh, const ushort* __restrict__ Bl,   // Ghat hi/lo [640][KP]
    const float* __restrict__ xsrc, float* __restrict__ qpart) {
    __shared__ ushort As_h[2][128][32];
    __shared__ ushort As_l[2][128][32];
    __shared__ ushort Bs_h[2][128][32];
    __shared__ ushort Bs_l[2][128][32];
    const int tid = threadIdx.x;
    const int col0 = blockIdx.x * 128;
    const int row0 = blockIdx.y * 128;
    const int kend = (KP < col0 + 128) ? KP : (col0 + 128);   // triangular cut
    const int wave = tid >> 6, lane = tid & 63;
    const int wr = (wave >> 1) * 64, wc = (wave & 1) * 64;
    const int lrow = lane & 15, kb = (lane >> 4) * 8;

    const int s0 = wave * 32 + (lane >> 2);
    const int skh = (lane & 3) * 8;
    const ushort* gAh0 = Ah + (size_t)(row0 + s0) * KP + skh;
    const ushort* gAl0 = Al + (size_t)(row0 + s0) * KP + skh;
    const ushort* gBh0 = Bh + (size_t)(col0 + s0) * KP + skh;
    const ushort* gBl0 = Bl + (size_t)(col0 + s0) * KP + skh;
    const size_t rstep = (size_t)16 * KP;

    f32x4 acc[4][4];
    const f32x4 zero = {0.f, 0.f, 0.f, 0.f};
#pragma unroll
    for (int i = 0; i < 4; i++)
#pragma unroll
        for (int j = 0; j < 4; j++) acc[i][j] = zero;

    auto stage = [&](int buf, int k0) {
        gl_lds16(gAh0 + k0, &As_h[buf][wave * 32][0]);
        gl_lds16(gAh0 + rstep + k0, &As_h[buf][wave * 32 + 16][0]);
        gl_lds16(gAl0 + k0, &As_l[buf][wave * 32][0]);
        gl_lds16(gAl0 + rstep + k0, &As_l[buf][wave * 32 + 16][0]);
        gl_lds16(gBh0 + k0, &Bs_h[buf][wave * 32][0]);
        gl_lds16(gBh0 + rstep + k0, &Bs_h[buf][wave * 32 + 16][0]);
        gl_lds16(gBl0 + k0, &Bs_l[buf][wave * 32][0]);
        gl_lds16(gBl0 + rstep + k0, &Bs_l[buf][wave * 32 + 16][0]);
    };
    auto compute = [&](int buf) {
        bf16x8 ah[4], al[4], bh[4], bl[4];
#pragma unroll
        for (int i = 0; i < 4; i++) {
            ah[i] = *reinterpret_cast<const bf16x8*>(&As_h[buf][wr + i * 16 + lrow][kb]);
            al[i] = *reinterpret_cast<const bf16x8*>(&As_l[buf][wr + i * 16 + lrow][kb]);
            bh[i] = *reinterpret_cast<const bf16x8*>(&Bs_h[buf][wc + i * 16 + lrow][kb]);
            bl[i] = *reinterpret_cast<const bf16x8*>(&Bs_l[buf][wc + i * 16 + lrow][kb]);
        }
#pragma unroll
        for (int i = 0; i < 4; i++)
#pragma unroll
            for (int j = 0; j < 4; j++) {
                acc[i][j] = __builtin_amdgcn_mfma_f32_16x16x32_bf16(ah[i], bh[j], acc[i][j], 0, 0, 0);
                acc[i][j] = __builtin_amdgcn_mfma_f32_16x16x32_bf16(ah[i], bl[j], acc[i][j], 0, 0, 0);
                acc[i][j] = __builtin_amdgcn_mfma_f32_16x16x32_bf16(al[i], bh[j], acc[i][j], 0, 0, 0);
            }
    };

    stage(0, 0);
    __syncthreads();
    int cur = 0;
    for (int k0 = 32; k0 < kend; k0 += 32) {
        stage(cur ^ 1, k0);
        compute(cur);
        __syncthreads();
        cur ^= 1;
    }
    compute(cur);

    float* qp = qpart + (size_t)blockIdx.x * M1;
#pragma unroll
    for (int i = 0; i < 4; i++) {
#pragma unroll
        for (int reg = 0; reg < 4; reg++) {
            const int gm = row0 + wr + i * 16 + (lane >> 4) * 4 + reg;
            float part = 0.f;
#pragma unroll
            for (int j = 0; j < 4; j++) {
                const int gn = col0 + wc + j * 16 + lrow;
                const float xv = (gn < CC) ? xsrc[(size_t)gm * CC + gn] : 0.f;
                part += acc[i][j][reg] * xv;
            }
#pragma unroll
            for (int o = 1; o < 16; o <<= 1) part += __shfl_xor(part, o, 64);
            if ((lane & 15) == 0) atomicAdd(&qp[gm], part);  // 2 commutative adds/cell: deterministic
        }
    }
}

// ---------- center row -> fp64 normalized (one block per batch) ----------
__global__ __launch_bounds__(256) void center_kernel(const float* __restrict__ x,
                                                     double* __restrict__ xcn) {
    __shared__ double red[4];
    const int b = blockIdx.x, tid = threadIdx.x;
    const float* xc = x + ((size_t)(b * LL + LL / 2)) * CC;
    double s = 0.0;
    for (int c = tid; c < CC; c += 256) { double v = xc[c]; s += v * v; }
#pragma unroll
    for (int o = 32; o > 0; o >>= 1) s += __shfl_down(s, o, 64);
    if ((tid & 63) == 0) red[tid >> 6] = s;
    __syncthreads();
    const double tot = red[0] + red[1] + red[2] + red[3];
    const double invc = 1.0 / (sqrt(tot / (double)CC) + 1e-6);
    for (int c = tid; c < CC; c += 256) xcn[(size_t)b * CC + c] = (double)xc[c] * invc;
}

// ---------- t1[b][e] = <W'_e, xcn_b>, one wave per (b,e) ----------
__global__ __launch_bounds__(256) void gram1_kernel(const float* __restrict__ winp,
                                                    const double* __restrict__ xcn,
                                                    double* __restrict__ t1) {
    const int b = blockIdx.y;
    const int wave = threadIdx.x >> 6, lane = threadIdx.x & 63;
    const int e = blockIdx.x * 4 + wave;
    const float* wr = winp + (size_t)e * CC;
    const double* xb = xcn + (size_t)b * CC;
    double s = 0.0;
    for (int c = lane; c < CC; c += 64) s += (double)wr[c] * xb[c];
#pragma unroll
    for (int o = 32; o > 0; o >>= 1) s += __shfl_down(s, o, 64);
    if (lane == 0) t1[(size_t)b * EE + e] = s;
}

// ---------- g[b][c] = <W'T_c, t1_b>, one wave per (b,c) ----------
__global__ __launch_bounds__(256) void gram2_kernel(const float* __restrict__ winpT,
                                                    const double* __restrict__ t1,
                                                    double* __restrict__ g) {
    const int b = blockIdx.y;
    const int wave = threadIdx.x >> 6, lane = threadIdx.x & 63;
    const int c = blockIdx.x * 4 + wave;
    if (c >= CC) return;
    const float* wr = winpT + (size_t)c * EE;
    const double* tb = t1 + (size_t)b * EE;
    double s = 0.0;
    for (int e = lane; e < EE; e += 64) s += (double)wr[e] * tb[e];
#pragma unroll
    for (int o = 32; o > 0; o >>= 1) s += __shfl_down(s, o, 64);
    if (lane == 0) g[(size_t)b * CC + c] = s;
}

// ---------- top-k; sim computed inline: sim = dval / sqrt(sum qpart) ----------
__global__ __launch_bounds__(1024) void topk_kernel(const double* __restrict__ dval,
                                                    const float* __restrict__ qpart,
                                                    int* __restrict__ idx) {
    __shared__ unsigned long long keys[4096];
    const int b = blockIdx.x;
    for (int i = threadIdx.x; i < 4096; i += 1024) {
        const int r = b * 4096 + i;
        double q = 0.0;
#pragma unroll
        for (int t5 = 0; t5 < NQT; t5++) q += (double)qpart[(size_t)t5 * M1 + r];
        const float sv = (float)(dval[r] / sqrt(fmax(q, 1e-30)));
        unsigned u = __float_as_uint(sv);
        u = (u & 0x80000000u) ? ~u : (u | 0x80000000u);
        keys[i] = ((unsigned long long)(~u) << 32) | (unsigned)i;
    }
    __syncthreads();
    for (int size = 2; size <= 4096; size <<= 1) {
        for (int stride = size >> 1; stride > 0; stride >>= 1) {
#pragma unroll 1
            for (int t = threadIdx.x; t < 2048; t += 1024) {
                int low = t & (stride - 1);
                int pos = ((t - low) << 1) + low;
                bool up = ((pos & size) == 0);
                unsigned long long ka = keys[pos], kb = keys[pos + stride];
                if ((ka > kb) == up) { keys[pos] = kb; keys[pos + stride] = ka; }
            }
            __syncthreads();
        }
    }
    for (int t = threadIdx.x; t < KT; t += 1024) idx[b * KT + t] = (int)(keys[t] & 0xffffffffu);
}

// ---------- gather selected x rows (hi/lo) + inv; rows >= M2 zeroed; pos map ----------
__global__ __launch_bounds__(256) void gatherx_kernel(const ushort* __restrict__ xh,
                                                      const ushort* __restrict__ xl,
                                                      const float* __restrict__ inv,
                                                      const int* __restrict__ idx,
                                                      ushort* __restrict__ sh,
                                                      ushort* __restrict__ sl,
                                                      float* __restrict__ invsel,
                                                      int* __restrict__ pos) {
    const int r = blockIdx.x, t = threadIdx.x;
    if (r >= M2) {
        if (t < 144) {
            reinterpret_cast<ushort4*>(sh + (size_t)r * KP)[t] = make_ushort4(0, 0, 0, 0);
            reinterpret_cast<ushort4*>(sl + (size_t)r * KP)[t] = make_ushort4(0, 0, 0, 0);
        }
        return;
    }
    const int b = r / KT;
    const int src = b * LL + idx[r];
    if (t < 144) {
        reinterpret_cast<ushort4*>(sh + (size_t)r * KP)[t] =
            reinterpret_cast<const ushort4*>(xh + (size_t)src * KP)[t];
        reinterpret_cast<ushort4*>(sl + (size_t)r * KP)[t] =
            reinterpret_cast<const ushort4*>(xl + (size_t)src * KP)[t];
    }
    if (t == 0) {
        invsel[r] = inv[src];
        pos[src] = r;   // reverse map for fused output
    }
}

// ---------- 19-tap causal depthwise conv on selected rows -> bf16 hi/lo for GEMM2 ----------
__global__ __launch_bounds__(256) void conv19_kernel(const float* __restrict__ xps,
                                                     const float* __restrict__ ck19,
                                                     ushort* __restrict__ oh,
                                                     ushort* __restrict__ ol) {
    const int r = blockIdx.x, t = threadIdx.x;
    ushort* ph = oh + (size_t)r * KP2;
    ushort* pl = ol + (size_t)r * KP2;
    if (r >= M2) {
        for (int e = t; e < KP2; e += 256) { ph[e] = 0; pl[e] = 0; }
        return;
    }
    const int b = r / KT, tt = r - b * KT;
    const int jmax = (tt < JC - 1) ? tt : (JC - 1);
    const float* base = xps + (size_t)r * EE;
    for (int e = t; e < KP2; e += 256) {
        float y = 0.f;
        if (e < EE) {
            const float* bp = base + e;
            for (int j = 0; j <= jmax; j++) y += ck19[j * EE + e] * bp[-(ptrdiff_t)j * EE];
        }
        ushort h = f2bf(y);
        ph[e] = h;
        pl[e] = f2bf(y - bf2f(h));
    }
}

// ---------- fused output: out[r] = x[r] + (pos[r]>=0 ? xproc[pos[r]] : 0), wave-per-row ----------
__global__ __launch_bounds__(256) void outfuse_kernel(const float* __restrict__ x,
                                                      const float* __restrict__ xproc,
                                                      const int* __restrict__ pos,
                                                      float* __restrict__ out) {
    const int wave = threadIdx.x >> 6, lane = threadIdx.x & 63;
    const int r = blockIdx.x * 4 + wave;
    const int p = pos[r];
    const float4* xr = reinterpret_cast<const float4*>(x + (size_t)r * CC);
    float4* orow = reinterpret_cast<float4*>(out + (size_t)r * CC);
    const float4* pr = (p >= 0) ? reinterpret_cast<const float4*>(xproc + (size_t)p * CC) : nullptr;
#pragma unroll
    for (int k = 0; k < 3; k++) {
        const int c = lane + k * 64;
        if (c < 138) {
            float4 v = xr[c];
            if (pr) {
                float4 a = pr[c];
                v = make_float4(v.x + a.x, v.y + a.y, v.z + a.z, v.w + a.w);
            }
            orow[c] = v;
        }
    }
}

extern "C" void kernel_launch(void* const* d_in, const int* in_sizes, int n_in,
                              void* d_out, int out_size, void* d_ws, size_t ws_size,
                              hipStream_t stream) {
    const float* x      = (const float*)d_in[0];
    const float* norm_w = (const float*)d_in[1];
    const float* w_in   = (const float*)d_in[2];
    const float* b_in   = (const float*)d_in[3];
    const float* w_out  = (const float*)d_in[4];
    const float* b_out  = (const float*)d_in[5];
    const float* Amat   = (const float*)d_in[6];
    const float* Bp     = (const float*)d_in[7];
    const float* Cp     = (const float*)d_in[8];
    const float* conv_w = (const float*)d_in[9];
    float* out = (float*)d_out;

    char* wsb = (char*)d_ws;
    size_t off = 0;
    auto take = [&](size_t bytes) {
        void* p = wsb + off;
        off += (bytes + 255) & ~(size_t)255;
        return p;
    };
    ushort* xh    = (ushort*)take((size_t)M1 * KP * 2);       // 37.7 MB
    ushort* xl    = (ushort*)take((size_t)M1 * KP * 2);       // 37.7 MB
    float*  winp  = (float*)take((size_t)EE * CC * 4);
    float*  winpT = (float*)take((size_t)EE * CC * 4);
    ushort* wh    = (ushort*)take((size_t)1152 * KP * 2);
    ushort* wl    = (ushort*)take((size_t)1152 * KP * 2);
    ushort* w2h   = (ushort*)take((size_t)640 * KP2 * 2);
    ushort* w2l   = (ushort*)take((size_t)640 * KP2 * 2);
    ushort* wth   = (ushort*)take((size_t)640 * KP2 * 2);
    ushort* wtl   = (ushort*)take((size_t)640 * KP2 * 2);
    float*  G     = (float*)take((size_t)640 * CC * 4);
    ushort* Gh    = (ushort*)take((size_t)640 * KP * 2);
    ushort* Gl    = (ushort*)take((size_t)640 * KP * 2);
    float*  inv   = (float*)take((size_t)M1 * 4);
    float*  qpart = (float*)take((size_t)NQT * M1 * 4);
    double* dval  = (double*)take((size_t)M1 * 8);
    int*    posm  = (int*)take((size_t)M1 * 4);
    int*    idxb  = (int*)take((size_t)BB * KT * 4);
    double* gbuf  = (double*)take((size_t)BB * CC * 8);
    double* xcn   = (double*)take((size_t)BB * CC * 8);
    double* t1b   = (double*)take((size_t)BB * EE * 8);
    float*  ck19  = (float*)take((size_t)JC * EE * 4);
    ushort* sh    = (ushort*)take((size_t)M2P * KP * 2);
    ushort* sl    = (ushort*)take((size_t)M2P * KP * 2);
    float*  invsel= (float*)take((size_t)M2P * 4);
    float*  xps   = (float*)take((size_t)M2P * EE * 4);
    ushort* o2h   = (ushort*)take((size_t)M2P * KP2 * 2);
    ushort* o2l   = (ushort*)take((size_t)M2P * KP2 * 2);
    float*  xproc = (float*)take((size_t)M2P * CC * 4);
    (void)ws_size;

    // --- fused prep: qpart=0, posm=-1, winp/winpT ---
    prep_kernel<<<(EE * CC + 255) / 256, 256, 0, stream>>>(w_in, norm_w, winp, winpT, qpart, posm);

    // --- gram chain (g_b ready before convx) ---
    center_kernel<<<BB, 256, 0, stream>>>(x, xcn);
    dim3 gg1(EE / 4, BB);
    gram1_kernel<<<gg1, 256, 0, stream>>>(winp, xcn, t1b);
    dim3 gg2(CC / 4, BB);
    gram2_kernel<<<gg2, 256, 0, stream>>>(winpT, t1b, gbuf);

    // --- fused weight conversions + taps ---
    wconv_fused<<<1152 + 640 + 640 + 1, 256, 0, stream>>>(
        winp, w_out, winpT, Amat, Bp, Cp, conv_w, wh, wl, w2h, w2l, wth, wtl, ck19);

    // --- convx: bf16 split + inv + fused fp64 numerator dot ---
    convx_kernel<<<M1 / 4, 256, 0, stream>>>(x, gbuf, xh, xl, inv, dval);

    // --- G = W'^T W' (split-bf16), triangular-masked (2L+D) for gemmq ---
    dim3 gG(5, 5);
    gemm_mfma<<<gG, 256, 0, stream>>>(wth, wtl, wth, wtl, nullptr, nullptr, G,
                                      CC, CC, CC, KP2, 0);
    convG_kernel<<<640, 256, 0, stream>>>(G, Gh, Gl);

    // --- q_r = x_r^T G x_r via masked Ghat (2-phase pipelined) ---
    dim3 gq(NQT, M1 / 128);
    gemm_mfma_q<<<gq, 256, 0, stream>>>(xh, xl, Gh, Gl, x, qpart);

    // --- topk (sim computed inline from dval/qpart) ---
    topk_kernel<<<BB, 1024, 0, stream>>>(dval, qpart, idxb);

    // --- selected rows only: xproj_sel = inv*(x_sel@W'^T) + b_in ---
    gatherx_kernel<<<M2P, 256, 0, stream>>>(xh, xl, inv, idxb, sh, sl, invsel, posm);
    dim3 g1(9, M2P / 128);
    gemm_mfma<<<g1, 256, 0, stream>>>(sh, sl, wh, wl, invsel, b_in, xps,
                                      EE, M2, EE, KP, 0);

    // --- conv4 ∘ ssm16 = single 19-tap depthwise causal conv ---
    conv19_kernel<<<M2P, 256, 0, stream>>>(xps, ck19, o2h, o2l);

    // --- gemm2 ---
    dim3 g3(5, M2P / 128);
    gemm_mfma<<<g3, 256, 0, stream>>>(o2h, o2l, w2h, w2l, nullptr, b_out, xproc,
                                      CC, M2, CC, KP2, 0);

    // --- fused output: out = x (+ xproc on selected rows) ---
    outfuse_kernel<<<M1 / 4, 256, 0, stream>>>(x, xproc, posm, out);
}

// Round 11
// 410.443 us; speedup vs baseline: 1.1164x; 1.1164x over previous
//
#include <hip/hip_runtime.h>
#include <hip/hip_bf16.h>

// Problem constants (fixed by reference)
#define BB 8
#define LL 4096
#define CC 552      // DIM
#define EE 1104     // EXP
#define KT 409      // top-k
#define M1 32768    // B*L
#define M2 3272     // B*KT
#define KP 576      // K padded (gemm over DIM)
#define KP2 1120    // K padded (gemm over EXP)
#define M2P 3328    // M2 padded to 26*128
#define JT 16       // SSM truncation taps (||A||^16 ~ 2e-13)
#define JC 19       // composed conv4 * ssm16 taps
#define NQT 5       // col tiles in gemmq (640/128)

typedef __attribute__((ext_vector_type(8))) short bf16x8;
typedef __attribute__((ext_vector_type(4))) float f32x4;

__device__ __forceinline__ ushort f2bf(float f) {
    unsigned u = __float_as_uint(f);
    return (ushort)((u + 0x7FFFu + ((u >> 16) & 1u)) >> 16);  // RNE
}
__device__ __forceinline__ float bf2f(ushort h) {
    return __uint_as_float(((unsigned)h) << 16);
}

// async global->LDS, 16B per lane; LDS dest = wave-uniform base + lane*16 [m97/m03]
__device__ __forceinline__ void gl_lds16(const ushort* g, ushort* l) {
    __builtin_amdgcn_global_load_lds(
        (const __attribute__((address_space(1))) void*)g,
        (__attribute__((address_space(3))) void*)l, 16, 0, 0);
}

// ---------- fused prep: qpart=0, posm=-1, winp/winpT ----------
__global__ void prep_kernel(const float* __restrict__ w_in, const float* __restrict__ norm_w,
                            float* __restrict__ winp, float* __restrict__ winpT,
                            float* __restrict__ qpart, int* __restrict__ posm) {
    int i = blockIdx.x * blockDim.x + threadIdx.x;
    if (i < NQT * M1) qpart[i] = 0.f;
    if (i < M1) posm[i] = -1;
    if (i < EE * CC) {
        int c = i % CC, e = i / CC;
        float v = w_in[i] * norm_w[c];
        winp[i] = v;
        winpT[(size_t)c * EE + e] = v;
    }
}

// ---------- convx: wave-per-row; bf16 hi/lo + inv + fp64 dval = <x_r, g_b> ----------
__global__ __launch_bounds__(256) void convx_kernel(const float* __restrict__ x,
                                                    const double* __restrict__ gbuf,
                                                    ushort* __restrict__ xh, ushort* __restrict__ xl,
                                                    float* __restrict__ inv,
                                                    double* __restrict__ dval) {
    const int wave = threadIdx.x >> 6, lane = threadIdx.x & 63;
    const int r = blockIdx.x * 4 + wave;
    const int b = r >> 12;
    const float* xr = x + (size_t)r * CC;
    const double* gb = gbuf + (size_t)b * CC;
    ushort* oh = xh + (size_t)r * KP;
    ushort* ol = xl + (size_t)r * KP;
    float ss = 0.f;
    double d = 0.0;
#pragma unroll
    for (int k = 0; k < 3; k++) {
        const int c = lane + k * 64;
        if (c < 144) {
            float4 v = make_float4(0.f, 0.f, 0.f, 0.f);
            if (c < 138) {
                v = reinterpret_cast<const float4*>(xr)[c];
                ss += v.x * v.x + v.y * v.y + v.z * v.z + v.w * v.w;
                const double* gp = gb + c * 4;
                d += (double)v.x * gp[0] + (double)v.y * gp[1] +
                     (double)v.z * gp[2] + (double)v.w * gp[3];
            }
            ushort4 h, l;
            h.x = f2bf(v.x); l.x = f2bf(v.x - bf2f(h.x));
            h.y = f2bf(v.y); l.y = f2bf(v.y - bf2f(h.y));
            h.z = f2bf(v.z); l.z = f2bf(v.z - bf2f(h.z));
            h.w = f2bf(v.w); l.w = f2bf(v.w - bf2f(h.w));
            reinterpret_cast<ushort4*>(oh)[c] = h;
            reinterpret_cast<ushort4*>(ol)[c] = l;
        }
    }
#pragma unroll
    for (int o = 32; o > 0; o >>= 1) { ss += __shfl_down(ss, o, 64); d += __shfl_down(d, o, 64); }
    if (lane == 0) {
        inv[r] = 1.f / (sqrtf(ss / (float)CC) + 1e-6f);
        dval[r] = d;
    }
}

// ---------- device bodies for fused weight conversions ----------
__device__ __forceinline__ void conv_row_kp_hi(const float* __restrict__ src, int n, int nvalid,
                                               ushort* __restrict__ wh, int t) {
    if (t >= 144) return;
    float4 v = make_float4(0.f, 0.f, 0.f, 0.f);
    if (n < nvalid && t < 138) v = reinterpret_cast<const float4*>(src + (size_t)n * CC)[t];
    ushort4 h;
    h.x = f2bf(v.x); h.y = f2bf(v.y); h.z = f2bf(v.z); h.w = f2bf(v.w);
    reinterpret_cast<ushort4*>(wh + (size_t)n * KP)[t] = h;
}

__device__ __forceinline__ void conv_row_kp2_hi(const float* __restrict__ src, int n,
                                                ushort* __restrict__ wh, int t) {
    for (int i = t; i < KP2 / 4; i += 256) {
        float4 v = make_float4(0.f, 0.f, 0.f, 0.f);
        if (n < CC && i < EE / 4) v = reinterpret_cast<const float4*>(src + (size_t)n * EE)[i];
        ushort4 h;
        h.x = f2bf(v.x); h.y = f2bf(v.y); h.z = f2bf(v.z); h.w = f2bf(v.w);
        reinterpret_cast<ushort4*>(wh + (size_t)n * KP2)[i] = h;
    }
}

__device__ __forceinline__ void conv_row_kp2_full(const float* __restrict__ src, int n,
                                                  ushort* __restrict__ wh, ushort* __restrict__ wl, int t) {
    for (int i = t; i < KP2 / 4; i += 256) {
        float4 v = make_float4(0.f, 0.f, 0.f, 0.f);
        if (n < CC && i < EE / 4) v = reinterpret_cast<const float4*>(src + (size_t)n * EE)[i];
        ushort4 h, l;
        h.x = f2bf(v.x); l.x = f2bf(v.x - bf2f(h.x));
        h.y = f2bf(v.y); l.y = f2bf(v.y - bf2f(h.y));
        h.z = f2bf(v.z); l.z = f2bf(v.z - bf2f(h.z));
        h.w = f2bf(v.w); l.w = f2bf(v.w - bf2f(h.w));
        reinterpret_cast<ushort4*>(wh + (size_t)n * KP2)[i] = h;
        reinterpret_cast<ushort4*>(wl + (size_t)n * KP2)[i] = l;
    }
}

__device__ void taps19_body(const float* __restrict__ A, const float* __restrict__ Bp,
                            const float* __restrict__ Cp, const float* __restrict__ conv_w,
                            float* __restrict__ ck19, int t) {
    __shared__ float Ash[256];
    __shared__ float vmat[JT][16];
    Ash[t] = A[t];
    __syncthreads();
    if (t < 16) vmat[0][t] = 1.f / (1.f + expf(-Bp[t]));
    __syncthreads();
    for (int j = 1; j < JT; j++) {
        float nv = 0.f;
        if (t < 16) {
#pragma unroll
            for (int s2 = 0; s2 < 16; s2++) nv += Ash[t * 16 + s2] * vmat[j - 1][s2];
        }
        __syncthreads();
        if (t < 16) vmat[j][t] = nv;
        __syncthreads();
    }
    for (int e = t; e < EE; e += 256) {
        float sc[16];
#pragma unroll
        for (int s = 0; s < 16; s++) sc[s] = 1.f / (1.f + expf(-Cp[e * 16 + s]));
        float ck[JT];
#pragma unroll
        for (int j = 0; j < JT; j++) {
            float kk = 0.f;
#pragma unroll
            for (int s = 0; s < 16; s++) kk += sc[s] * vmat[j][s];
            ck[j] = kk;
        }
        float w4[4];
#pragma unroll
        for (int i = 0; i < 4; i++) w4[i] = conv_w[e * 4 + 3 - i];
#pragma unroll
        for (int m = 0; m < JC; m++) {
            float kk = 0.f;
#pragma unroll
            for (int i = 0; i < 4; i++) {
                int jm = m - i;
                if (jm >= 0 && jm < JT) kk += w4[i] * ck[jm];
            }
            ck19[m * EE + e] = kk;
        }
    }
}

// ---------- fused weight conversions + taps ----------
__global__ __launch_bounds__(256) void wconv_fused(
    const float* __restrict__ winp, const float* __restrict__ w_out,
    const float* __restrict__ winpT,
    const float* __restrict__ A, const float* __restrict__ Bp,
    const float* __restrict__ Cp, const float* __restrict__ conv_w,
    ushort* __restrict__ wh,
    ushort* __restrict__ w2h,
    ushort* __restrict__ wth, ushort* __restrict__ wtl,
    float* __restrict__ ck19) {
    int bx = blockIdx.x;
    const int t = threadIdx.x;
    if (bx < 1152) { conv_row_kp_hi(winp, bx, EE, wh, t); return; }
    bx -= 1152;
    if (bx < 640) { conv_row_kp2_hi(w_out, bx, w2h, t); return; }
    bx -= 640;
    if (bx < 640) { conv_row_kp2_full(winpT, bx, wth, wtl, t); return; }
    taps19_body(A, Bp, Cp, conv_w, ck19, t);
}

// ---------- triangular-masked conversion of G: Ghat[n][k] = G[n][k]*(n>k?2:n==k?1:0) ----------
__global__ __launch_bounds__(256) void convG_kernel(const float* __restrict__ G,
                                                    ushort* __restrict__ gh, ushort* __restrict__ gl) {
    const int n = blockIdx.x, t = threadIdx.x;
    if (t >= 144) return;
    float4 v = make_float4(0.f, 0.f, 0.f, 0.f);
    if (n < CC && t < 138) {
        v = reinterpret_cast<const float4*>(G + (size_t)n * CC)[t];
        const int k0 = t * 4;
        float m0 = (n > k0 + 0) ? 2.f : (n == k0 + 0) ? 1.f : 0.f;
        float m1 = (n > k0 + 1) ? 2.f : (n == k0 + 1) ? 1.f : 0.f;
        float m2 = (n > k0 + 2) ? 2.f : (n == k0 + 2) ? 1.f : 0.f;
        float m3 = (n > k0 + 3) ? 2.f : (n == k0 + 3) ? 1.f : 0.f;
        v = make_float4(v.x * m0, v.y * m1, v.z * m2, v.w * m3);
    }
    ushort4 h, l;
    h.x = f2bf(v.x); l.x = f2bf(v.x - bf2f(h.x));
    h.y = f2bf(v.y); l.y = f2bf(v.y - bf2f(h.y));
    h.z = f2bf(v.z); l.z = f2bf(v.z - bf2f(h.z));
    h.w = f2bf(v.w); l.w = f2bf(v.w - bf2f(h.w));
    reinterpret_cast<ushort4*>(gh + (size_t)n * KP)[t] = h;
    reinterpret_cast<ushort4*>(gl + (size_t)n * KP)[t] = l;
}

// ---------- 3-product split-bf16 MFMA GEMM, 2-phase prefetch (used for gemmG only) ----------
__global__ __launch_bounds__(256) void gemm_mfma(
    const ushort* __restrict__ Ah, const ushort* __restrict__ Al,   // [Mp][Kp]
    const ushort* __restrict__ Bh, const ushort* __restrict__ Bl,   // [Np][Kp]
    const float* __restrict__ rowscale, const float* __restrict__ bias,
    float* __restrict__ C, int ldc, int M, int N, int Kp, int r0) {
    __shared__ ushort As_h[2][128][32];
    __shared__ ushort As_l[2][128][32];
    __shared__ ushort Bs_h[2][128][32];
    __shared__ ushort Bs_l[2][128][32];
    const int tid = threadIdx.x;
    const int col0 = blockIdx.x * 128;
    const int row0 = blockIdx.y * 128;
    const int wave = tid >> 6, lane = tid & 63;
    const int wr = (wave >> 1) * 64, wc = (wave & 1) * 64;
    const int lrow = lane & 15, kb = (lane >> 4) * 8;

    const int s0 = wave * 32 + (lane >> 2);
    const int skh = (lane & 3) * 8;
    const ushort* gAh0 = Ah + (size_t)(row0 + s0) * Kp + skh;
    const ushort* gAl0 = Al + (size_t)(row0 + s0) * Kp + skh;
    const ushort* gBh0 = Bh + (size_t)(col0 + s0) * Kp + skh;
    const ushort* gBl0 = Bl + (size_t)(col0 + s0) * Kp + skh;
    const size_t rstep = (size_t)16 * Kp;

    f32x4 acc[4][4];
    const f32x4 zero = {0.f, 0.f, 0.f, 0.f};
#pragma unroll
    for (int i = 0; i < 4; i++)
#pragma unroll
        for (int j = 0; j < 4; j++) acc[i][j] = zero;

    auto stage = [&](int buf, int k0) {
        gl_lds16(gAh0 + k0, &As_h[buf][wave * 32][0]);
        gl_lds16(gAh0 + rstep + k0, &As_h[buf][wave * 32 + 16][0]);
        gl_lds16(gAl0 + k0, &As_l[buf][wave * 32][0]);
        gl_lds16(gAl0 + rstep + k0, &As_l[buf][wave * 32 + 16][0]);
        gl_lds16(gBh0 + k0, &Bs_h[buf][wave * 32][0]);
        gl_lds16(gBh0 + rstep + k0, &Bs_h[buf][wave * 32 + 16][0]);
        gl_lds16(gBl0 + k0, &Bs_l[buf][wave * 32][0]);
        gl_lds16(gBl0 + rstep + k0, &Bs_l[buf][wave * 32 + 16][0]);
    };
    auto compute = [&](int buf) {
        bf16x8 ah[4], al[4], bh[4], bl[4];
#pragma unroll
        for (int i = 0; i < 4; i++) {
            ah[i] = *reinterpret_cast<const bf16x8*>(&As_h[buf][wr + i * 16 + lrow][kb]);
            al[i] = *reinterpret_cast<const bf16x8*>(&As_l[buf][wr + i * 16 + lrow][kb]);
            bh[i] = *reinterpret_cast<const bf16x8*>(&Bs_h[buf][wc + i * 16 + lrow][kb]);
            bl[i] = *reinterpret_cast<const bf16x8*>(&Bs_l[buf][wc + i * 16 + lrow][kb]);
        }
#pragma unroll
        for (int i = 0; i < 4; i++)
#pragma unroll
            for (int j = 0; j < 4; j++) {
                acc[i][j] = __builtin_amdgcn_mfma_f32_16x16x32_bf16(ah[i], bh[j], acc[i][j], 0, 0, 0);
                acc[i][j] = __builtin_amdgcn_mfma_f32_16x16x32_bf16(ah[i], bl[j], acc[i][j], 0, 0, 0);
                acc[i][j] = __builtin_amdgcn_mfma_f32_16x16x32_bf16(al[i], bh[j], acc[i][j], 0, 0, 0);
            }
    };

    stage(0, 0);
    __syncthreads();
    int cur = 0;
    for (int k0 = 32; k0 < Kp; k0 += 32) {
        stage(cur ^ 1, k0);
        compute(cur);
        __syncthreads();
        cur ^= 1;
    }
    compute(cur);

#pragma unroll
    for (int i = 0; i < 4; i++) {
        const int gmb = r0 + row0 + wr + i * 16 + (lane >> 4) * 4;
#pragma unroll
        for (int reg = 0; reg < 4; reg++) {
            const int gm = gmb + reg;
            if (gm < M) {
                const float rs = rowscale ? rowscale[gm] : 1.f;
#pragma unroll
                for (int j = 0; j < 4; j++) {
                    const int gn = col0 + wc + j * 16 + lrow;
                    if (gn < N) C[(size_t)gm * ldc + gn] = acc[i][j][reg] * rs + (bias ? bias[gn] : 0.f);
                }
            }
        }
    }
}

// ---------- single-product bf16 GEMM (selected path; ordering-independent, abs-err ~1e-3) ----------
__global__ __launch_bounds__(256) void gemm_mfma_1x(
    const ushort* __restrict__ Ah,     // [Mp][Kp] bf16
    const ushort* __restrict__ Bh,     // [Np][Kp] bf16
    const float* __restrict__ rowscale, const float* __restrict__ bias,
    float* __restrict__ C, int ldc, int M, int N, int Kp, int r0) {
    __shared__ ushort As[2][128][32];
    __shared__ ushort Bs[2][128][32];
    const int tid = threadIdx.x;
    const int col0 = blockIdx.x * 128;
    const int row0 = blockIdx.y * 128;
    const int wave = tid >> 6, lane = tid & 63;
    const int wr = (wave >> 1) * 64, wc = (wave & 1) * 64;
    const int lrow = lane & 15, kb = (lane >> 4) * 8;

    const int s0 = wave * 32 + (lane >> 2);
    const int skh = (lane & 3) * 8;
    const ushort* gA0 = Ah + (size_t)(row0 + s0) * Kp + skh;
    const ushort* gB0 = Bh + (size_t)(col0 + s0) * Kp + skh;
    const size_t rstep = (size_t)16 * Kp;

    f32x4 acc[4][4];
    const f32x4 zero = {0.f, 0.f, 0.f, 0.f};
#pragma unroll
    for (int i = 0; i < 4; i++)
#pragma unroll
        for (int j = 0; j < 4; j++) acc[i][j] = zero;

    auto stage = [&](int buf, int k0) {
        gl_lds16(gA0 + k0, &As[buf][wave * 32][0]);
        gl_lds16(gA0 + rstep + k0, &As[buf][wave * 32 + 16][0]);
        gl_lds16(gB0 + k0, &Bs[buf][wave * 32][0]);
        gl_lds16(gB0 + rstep + k0, &Bs[buf][wave * 32 + 16][0]);
    };
    auto compute = [&](int buf) {
        bf16x8 ah[4], bh[4];
#pragma unroll
        for (int i = 0; i < 4; i++) {
            ah[i] = *reinterpret_cast<const bf16x8*>(&As[buf][wr + i * 16 + lrow][kb]);
            bh[i] = *reinterpret_cast<const bf16x8*>(&Bs[buf][wc + i * 16 + lrow][kb]);
        }
#pragma unroll
        for (int i = 0; i < 4; i++)
#pragma unroll
            for (int j = 0; j < 4; j++)
                acc[i][j] = __builtin_amdgcn_mfma_f32_16x16x32_bf16(ah[i], bh[j], acc[i][j], 0, 0, 0);
    };

    stage(0, 0);
    __syncthreads();
    int cur = 0;
    for (int k0 = 32; k0 < Kp; k0 += 32) {
        stage(cur ^ 1, k0);
        compute(cur);
        __syncthreads();
        cur ^= 1;
    }
    compute(cur);

#pragma unroll
    for (int i = 0; i < 4; i++) {
        const int gmb = r0 + row0 + wr + i * 16 + (lane >> 4) * 4;
#pragma unroll
        for (int reg = 0; reg < 4; reg++) {
            const int gm = gmb + reg;
            if (gm < M) {
                const float rs = rowscale ? rowscale[gm] : 1.f;
#pragma unroll
                for (int j = 0; j < 4; j++) {
                    const int gn = col0 + wc + j * 16 + lrow;
                    if (gn < N) C[(size_t)gm * ldc + gn] = acc[i][j][reg] * rs + (bias ? bias[gn] : 0.f);
                }
            }
        }
    }
}

// ---------- gemmq: XCD-swizzled 1D grid; 3-product; fused q epilogue; triangular kend ----------
__global__ __launch_bounds__(256) void gemm_mfma_q(
    const ushort* __restrict__ Ah, const ushort* __restrict__ Al,   // x hi/lo [M1][KP]
    const ushort* __restrict__ Bh, const ushort* __restrict__ Bl,   // Ghat hi/lo [640][KP]
    const float* __restrict__ xsrc, float* __restrict__ qpart) {
    __shared__ ushort As_h[2][128][32];
    __shared__ ushort As_l[2][128][32];
    __shared__ ushort Bs_h[2][128][32];
    __shared__ ushort Bs_l[2][128][32];
    const int tid = threadIdx.x;
    // bijective XCD swizzle (m204): nwg=1280, 160/XCD; co-locates the 5 col-tiles
    // of each row-tile on one XCD so their shared A k-tiles become L2 hits [T1].
    const int orig = blockIdx.x;
    const int work = (orig & 7) * 160 + (orig >> 3);
    const int ct = work % NQT;          // col tile
    const int rt = work / NQT;          // row tile
    const int col0 = ct * 128;
    const int row0 = rt * 128;
    const int kend = (KP < col0 + 128) ? KP : (col0 + 128);   // triangular cut
    const int wave = tid >> 6, lane = tid & 63;
    const int wr = (wave >> 1) * 64, wc = (wave & 1) * 64;
    const int lrow = lane & 15, kb = (lane >> 4) * 8;

    const int s0 = wave * 32 + (lane >> 2);
    const int skh = (lane & 3) * 8;
    const ushort* gAh0 = Ah + (size_t)(row0 + s0) * KP + skh;
    const ushort* gAl0 = Al + (size_t)(row0 + s0) * KP + skh;
    const ushort* gBh0 = Bh + (size_t)(col0 + s0) * KP + skh;
    const ushort* gBl0 = Bl + (size_t)(col0 + s0) * KP + skh;
    const size_t rstep = (size_t)16 * KP;

    f32x4 acc[4][4];
    const f32x4 zero = {0.f, 0.f, 0.f, 0.f};
#pragma unroll
    for (int i = 0; i < 4; i++)
#pragma unroll
        for (int j = 0; j < 4; j++) acc[i][j] = zero;

    auto stage = [&](int buf, int k0) {
        gl_lds16(gAh0 + k0, &As_h[buf][wave * 32][0]);
        gl_lds16(gAh0 + rstep + k0, &As_h[buf][wave * 32 + 16][0]);
        gl_lds16(gAl0 + k0, &As_l[buf][wave * 32][0]);
        gl_lds16(gAl0 + rstep + k0, &As_l[buf][wave * 32 + 16][0]);
        gl_lds16(gBh0 + k0, &Bs_h[buf][wave * 32][0]);
        gl_lds16(gBh0 + rstep + k0, &Bs_h[buf][wave * 32 + 16][0]);
        gl_lds16(gBl0 + k0, &Bs_l[buf][wave * 32][0]);
        gl_lds16(gBl0 + rstep + k0, &Bs_l[buf][wave * 32 + 16][0]);
    };
    auto compute = [&](int buf) {
        bf16x8 ah[4], al[4], bh[4], bl[4];
#pragma unroll
        for (int i = 0; i < 4; i++) {
            ah[i] = *reinterpret_cast<const bf16x8*>(&As_h[buf][wr + i * 16 + lrow][kb]);
            al[i] = *reinterpret_cast<const bf16x8*>(&As_l[buf][wr + i * 16 + lrow][kb]);
            bh[i] = *reinterpret_cast<const bf16x8*>(&Bs_h[buf][wc + i * 16 + lrow][kb]);
            bl[i] = *reinterpret_cast<const bf16x8*>(&Bs_l[buf][wc + i * 16 + lrow][kb]);
        }
#pragma unroll
        for (int i = 0; i < 4; i++)
#pragma unroll
            for (int j = 0; j < 4; j++) {
                acc[i][j] = __builtin_amdgcn_mfma_f32_16x16x32_bf16(ah[i], bh[j], acc[i][j], 0, 0, 0);
                acc[i][j] = __builtin_amdgcn_mfma_f32_16x16x32_bf16(ah[i], bl[j], acc[i][j], 0, 0, 0);
                acc[i][j] = __builtin_amdgcn_mfma_f32_16x16x32_bf16(al[i], bh[j], acc[i][j], 0, 0, 0);
            }
    };

    stage(0, 0);
    __syncthreads();
    int cur = 0;
    for (int k0 = 32; k0 < kend; k0 += 32) {
        stage(cur ^ 1, k0);
        compute(cur);
        __syncthreads();
        cur ^= 1;
    }
    compute(cur);

    float* qp = qpart + (size_t)ct * M1;
#pragma unroll
    for (int i = 0; i < 4; i++) {
#pragma unroll
        for (int reg = 0; reg < 4; reg++) {
            const int gm = row0 + wr + i * 16 + (lane >> 4) * 4 + reg;
            float part = 0.f;
#pragma unroll
            for (int j = 0; j < 4; j++) {
                const int gn = col0 + wc + j * 16 + lrow;
                const float xv = (gn < CC) ? xsrc[(size_t)gm * CC + gn] : 0.f;
                part += acc[i][j][reg] * xv;
            }
#pragma unroll
            for (int o = 1; o < 16; o <<= 1) part += __shfl_xor(part, o, 64);
            if ((lane & 15) == 0) atomicAdd(&qp[gm], part);  // 2 commutative adds/cell: deterministic
        }
    }
}

// ---------- center row -> fp64 normalized (one block per batch) ----------
__global__ __launch_bounds__(256) void center_kernel(const float* __restrict__ x,
                                                     double* __restrict__ xcn) {
    __shared__ double red[4];
    const int b = blockIdx.x, tid = threadIdx.x;
    const float* xc = x + ((size_t)(b * LL + LL / 2)) * CC;
    double s = 0.0;
    for (int c = tid; c < CC; c += 256) { double v = xc[c]; s += v * v; }
#pragma unroll
    for (int o = 32; o > 0; o >>= 1) s += __shfl_down(s, o, 64);
    if ((tid & 63) == 0) red[tid >> 6] = s;
    __syncthreads();
    const double tot = red[0] + red[1] + red[2] + red[3];
    const double invc = 1.0 / (sqrt(tot / (double)CC) + 1e-6);
    for (int c = tid; c < CC; c += 256) xcn[(size_t)b * CC + c] = (double)xc[c] * invc;
}

// ---------- t1[b][e] = <W'_e, xcn_b>, one wave per (b,e) ----------
__global__ __launch_bounds__(256) void gram1_kernel(const float* __restrict__ winp,
                                                    const double* __restrict__ xcn,
                                                    double* __restrict__ t1) {
    const int b = blockIdx.y;
    const int wave = threadIdx.x >> 6, lane = threadIdx.x & 63;
    const int e = blockIdx.x * 4 + wave;
    const float* wr = winp + (size_t)e * CC;
    const double* xb = xcn + (size_t)b * CC;
    double s = 0.0;
    for (int c = lane; c < CC; c += 64) s += (double)wr[c] * xb[c];
#pragma unroll
    for (int o = 32; o > 0; o >>= 1) s += __shfl_down(s, o, 64);
    if (lane == 0) t1[(size_t)b * EE + e] = s;
}

// ---------- g[b][c] = <W'T_c, t1_b>, one wave per (b,c) ----------
__global__ __launch_bounds__(256) void gram2_kernel(const float* __restrict__ winpT,
                                                    const double* __restrict__ t1,
                                                    double* __restrict__ g) {
    const int b = blockIdx.y;
    const int wave = threadIdx.x >> 6, lane = threadIdx.x & 63;
    const int c = blockIdx.x * 4 + wave;
    if (c >= CC) return;
    const float* wr = winpT + (size_t)c * EE;
    const double* tb = t1 + (size_t)b * EE;
    double s = 0.0;
    for (int e = lane; e < EE; e += 64) s += (double)wr[e] * tb[e];
#pragma unroll
    for (int o = 32; o > 0; o >>= 1) s += __shfl_down(s, o, 64);
    if (lane == 0) g[(size_t)b * CC + c] = s;
}

// ---------- top-k; sim computed inline: sim = dval / sqrt(sum qpart) ----------
__global__ __launch_bounds__(1024) void topk_kernel(const double* __restrict__ dval,
                                                    const float* __restrict__ qpart,
                                                    int* __restrict__ idx) {
    __shared__ unsigned long long keys[4096];
    const int b = blockIdx.x;
    for (int i = threadIdx.x; i < 4096; i += 1024) {
        const int r = b * 4096 + i;
        double q = 0.0;
#pragma unroll
        for (int t5 = 0; t5 < NQT; t5++) q += (double)qpart[(size_t)t5 * M1 + r];
        const float sv = (float)(dval[r] / sqrt(fmax(q, 1e-30)));
        unsigned u = __float_as_uint(sv);
        u = (u & 0x80000000u) ? ~u : (u | 0x80000000u);
        keys[i] = ((unsigned long long)(~u) << 32) | (unsigned)i;
    }
    __syncthreads();
    for (int size = 2; size <= 4096; size <<= 1) {
        for (int stride = size >> 1; stride > 0; stride >>= 1) {
#pragma unroll 1
            for (int t = threadIdx.x; t < 2048; t += 1024) {
                int low = t & (stride - 1);
                int pos = ((t - low) << 1) + low;
                bool up = ((pos & size) == 0);
                unsigned long long ka = keys[pos], kb = keys[pos + stride];
                if ((ka > kb) == up) { keys[pos] = kb; keys[pos + stride] = ka; }
            }
            __syncthreads();
        }
    }
    for (int t = threadIdx.x; t < KT; t += 1024) idx[b * KT + t] = (int)(keys[t] & 0xffffffffu);
}

// ---------- gather selected x rows (hi only) + inv; rows >= M2 zeroed; pos map ----------
__global__ __launch_bounds__(256) void gatherx_kernel(const ushort* __restrict__ xh,
                                                      const float* __restrict__ inv,
                                                      const int* __restrict__ idx,
                                                      ushort* __restrict__ sh,
                                                      float* __restrict__ invsel,
                                                      int* __restrict__ pos) {
    const int r = blockIdx.x, t = threadIdx.x;
    if (r >= M2) {
        if (t < 144) reinterpret_cast<ushort4*>(sh + (size_t)r * KP)[t] = make_ushort4(0, 0, 0, 0);
        return;
    }
    const int b = r / KT;
    const int src = b * LL + idx[r];
    if (t < 144) {
        reinterpret_cast<ushort4*>(sh + (size_t)r * KP)[t] =
            reinterpret_cast<const ushort4*>(xh + (size_t)src * KP)[t];
    }
    if (t == 0) {
        invsel[r] = inv[src];
        pos[src] = r;   // reverse map for fused output
    }
}

// ---------- 19-tap causal depthwise conv on selected rows -> bf16 (hi only) for GEMM2 ----------
__global__ __launch_bounds__(256) void conv19_kernel(const float* __restrict__ xps,
                                                     const float* __restrict__ ck19,
                                                     ushort* __restrict__ oh) {
    const int r = blockIdx.x, t = threadIdx.x;
    ushort* ph = oh + (size_t)r * KP2;
    if (r >= M2) {
        for (int e = t; e < KP2; e += 256) ph[e] = 0;
        return;
    }
    const int b = r / KT, tt = r - b * KT;
    const int jmax = (tt < JC - 1) ? tt : (JC - 1);
    const float* base = xps + (size_t)r * EE;
    for (int e = t; e < KP2; e += 256) {
        float y = 0.f;
        if (e < EE) {
            const float* bp = base + e;
            for (int j = 0; j <= jmax; j++) y += ck19[j * EE + e] * bp[-(ptrdiff_t)j * EE];
        }
        ph[e] = f2bf(y);
    }
}

// ---------- fused output: out[r] = x[r] + (pos[r]>=0 ? xproc[pos[r]] : 0), wave-per-row ----------
__global__ __launch_bounds__(256) void outfuse_kernel(const float* __restrict__ x,
                                                      const float* __restrict__ xproc,
                                                      const int* __restrict__ pos,
                                                      float* __restrict__ out) {
    const int wave = threadIdx.x >> 6, lane = threadIdx.x & 63;
    const int r = blockIdx.x * 4 + wave;
    const int p = pos[r];
    const float4* xr = reinterpret_cast<const float4*>(x + (size_t)r * CC);
    float4* orow = reinterpret_cast<float4*>(out + (size_t)r * CC);
    const float4* pr = (p >= 0) ? reinterpret_cast<const float4*>(xproc + (size_t)p * CC) : nullptr;
#pragma unroll
    for (int k = 0; k < 3; k++) {
        const int c = lane + k * 64;
        if (c < 138) {
            float4 v = xr[c];
            if (pr) {
                float4 a = pr[c];
                v = make_float4(v.x + a.x, v.y + a.y, v.z + a.z, v.w + a.w);
            }
            orow[c] = v;
        }
    }
}

extern "C" void kernel_launch(void* const* d_in, const int* in_sizes, int n_in,
                              void* d_out, int out_size, void* d_ws, size_t ws_size,
                              hipStream_t stream) {
    const float* x      = (const float*)d_in[0];
    const float* norm_w = (const float*)d_in[1];
    const float* w_in   = (const float*)d_in[2];
    const float* b_in   = (const float*)d_in[3];
    const float* w_out  = (const float*)d_in[4];
    const float* b_out  = (const float*)d_in[5];
    const float* Amat   = (const float*)d_in[6];
    const float* Bp     = (const float*)d_in[7];
    const float* Cp     = (const float*)d_in[8];
    const float* conv_w = (const float*)d_in[9];
    float* out = (float*)d_out;

    char* wsb = (char*)d_ws;
    size_t off = 0;
    auto take = [&](size_t bytes) {
        void* p = wsb + off;
        off += (bytes + 255) & ~(size_t)255;
        return p;
    };
    ushort* xh    = (ushort*)take((size_t)M1 * KP * 2);       // 37.7 MB
    ushort* xl    = (ushort*)take((size_t)M1 * KP * 2);       // 37.7 MB
    float*  winp  = (float*)take((size_t)EE * CC * 4);
    float*  winpT = (float*)take((size_t)EE * CC * 4);
    ushort* wh    = (ushort*)take((size_t)1152 * KP * 2);
    ushort* w2h   = (ushort*)take((size_t)640 * KP2 * 2);
    ushort* wth   = (ushort*)take((size_t)640 * KP2 * 2);
    ushort* wtl   = (ushort*)take((size_t)640 * KP2 * 2);
    float*  G     = (float*)take((size_t)640 * CC * 4);
    ushort* Gh    = (ushort*)take((size_t)640 * KP * 2);
    ushort* Gl    = (ushort*)take((size_t)640 * KP * 2);
    float*  inv   = (float*)take((size_t)M1 * 4);
    float*  qpart = (float*)take((size_t)NQT * M1 * 4);
    double* dval  = (double*)take((size_t)M1 * 8);
    int*    posm  = (int*)take((size_t)M1 * 4);
    int*    idxb  = (int*)take((size_t)BB * KT * 4);
    double* gbuf  = (double*)take((size_t)BB * CC * 8);
    double* xcn   = (double*)take((size_t)BB * CC * 8);
    double* t1b   = (double*)take((size_t)BB * EE * 8);
    float*  ck19  = (float*)take((size_t)JC * EE * 4);
    ushort* sh    = (ushort*)take((size_t)M2P * KP * 2);
    float*  invsel= (float*)take((size_t)M2P * 4);
    float*  xps   = (float*)take((size_t)M2P * EE * 4);
    ushort* o2h   = (ushort*)take((size_t)M2P * KP2 * 2);
    float*  xproc = (float*)take((size_t)M2P * CC * 4);
    (void)ws_size;

    // --- fused prep: qpart=0, posm=-1, winp/winpT ---
    prep_kernel<<<(EE * CC + 255) / 256, 256, 0, stream>>>(w_in, norm_w, winp, winpT, qpart, posm);

    // --- gram chain (g_b ready before convx) ---
    center_kernel<<<BB, 256, 0, stream>>>(x, xcn);
    dim3 gg1(EE / 4, BB);
    gram1_kernel<<<gg1, 256, 0, stream>>>(winp, xcn, t1b);
    dim3 gg2(CC / 4, BB);
    gram2_kernel<<<gg2, 256, 0, stream>>>(winpT, t1b, gbuf);

    // --- fused weight conversions + taps ---
    wconv_fused<<<1152 + 640 + 640 + 1, 256, 0, stream>>>(
        winp, w_out, winpT, Amat, Bp, Cp, conv_w, wh, w2h, wth, wtl, ck19);

    // --- convx: bf16 split + inv + fused fp64 numerator dot ---
    convx_kernel<<<M1 / 4, 256, 0, stream>>>(x, gbuf, xh, xl, inv, dval);

    // --- G = W'^T W' (split-bf16, 3-product), triangular-masked (2L+D) for gemmq ---
    dim3 gG(5, 5);
    gemm_mfma<<<gG, 256, 0, stream>>>(wth, wtl, wth, wtl, nullptr, nullptr, G,
                                      CC, CC, CC, KP2, 0);
    convG_kernel<<<640, 256, 0, stream>>>(G, Gh, Gl);

    // --- q_r = x_r^T G x_r via masked Ghat (XCD-swizzled, 2-phase) ---
    gemm_mfma_q<<<NQT * (M1 / 128), 256, 0, stream>>>(xh, xl, Gh, Gl, x, qpart);

    // --- topk (sim computed inline from dval/qpart) ---
    topk_kernel<<<BB, 1024, 0, stream>>>(dval, qpart, idxb);

    // --- selected rows only: xproj_sel = inv*(x_sel@W'^T) + b_in (bf16-single) ---
    gatherx_kernel<<<M2P, 256, 0, stream>>>(xh, inv, idxb, sh, invsel, posm);
    dim3 g1(9, M2P / 128);
    gemm_mfma_1x<<<g1, 256, 0, stream>>>(sh, wh, invsel, b_in, xps,
                                         EE, M2, EE, KP, 0);

    // --- conv4 ∘ ssm16 = single 19-tap depthwise causal conv (hi-only out) ---
    conv19_kernel<<<M2P, 256, 0, stream>>>(xps, ck19, o2h);

    // --- gemm2 (bf16-single) ---
    dim3 g3(5, M2P / 128);
    gemm_mfma_1x<<<g3, 256, 0, stream>>>(o2h, w2h, nullptr, b_out, xproc,
                                         CC, M2, CC, KP2, 0);

    // --- fused output: out = x (+ xproc on selected rows) ---
    outfuse_kernel<<<M1 / 4, 256, 0, stream>>>(x, xproc, posm, out);
}

// Round 12
// 365.835 us; speedup vs baseline: 1.2525x; 1.1219x over previous
//
#include <hip/hip_runtime.h>
#include <hip/hip_bf16.h>

// Problem constants (fixed by reference)
#define BB 8
#define LL 4096
#define CC 552      // DIM
#define EE 1104     // EXP
#define KT 409      // top-k
#define M1 32768    // B*L
#define M2 3272     // B*KT
#define KP 576      // K padded (gemm over DIM)
#define KP2 1120    // K padded (gemm over EXP)
#define M2P 3328    // M2 padded to 26*128
#define JT 16       // SSM truncation taps (||A||^16 ~ 2e-13)
#define JC 19       // composed conv4 * ssm16 taps
#define NQT 5       // col tiles in gemmq (640/128)
#define GKC 224     // gemmG K-chunk (1120/5)

typedef __attribute__((ext_vector_type(8))) short bf16x8;
typedef __attribute__((ext_vector_type(4))) float f32x4;

__device__ __forceinline__ ushort f2bf(float f) {
    unsigned u = __float_as_uint(f);
    return (ushort)((u + 0x7FFFu + ((u >> 16) & 1u)) >> 16);  // RNE
}
__device__ __forceinline__ float bf2f(ushort h) {
    return __uint_as_float(((unsigned)h) << 16);
}

// async global->LDS, 16B per lane; LDS dest = wave-uniform base + lane*16 [m97/m03]
__device__ __forceinline__ void gl_lds16(const ushort* g, ushort* l) {
    __builtin_amdgcn_global_load_lds(
        (const __attribute__((address_space(1))) void*)g,
        (__attribute__((address_space(3))) void*)l, 16, 0, 0);
}

// ---------- fused prep: qpart=0, posm=-1, winp/winpT ----------
__global__ void prep_kernel(const float* __restrict__ w_in, const float* __restrict__ norm_w,
                            float* __restrict__ winp, float* __restrict__ winpT,
                            float* __restrict__ qpart, int* __restrict__ posm) {
    int i = blockIdx.x * blockDim.x + threadIdx.x;
    if (i < NQT * M1) qpart[i] = 0.f;
    if (i < M1) posm[i] = -1;
    if (i < EE * CC) {
        int c = i % CC, e = i / CC;
        float v = w_in[i] * norm_w[c];
        winp[i] = v;
        winpT[(size_t)c * EE + e] = v;
    }
}

// ---------- convx: wave-per-row; bf16 hi/lo + inv + fp64 dval = <x_r, g_b> ----------
__global__ __launch_bounds__(256) void convx_kernel(const float* __restrict__ x,
                                                    const double* __restrict__ gbuf,
                                                    ushort* __restrict__ xh, ushort* __restrict__ xl,
                                                    float* __restrict__ inv,
                                                    double* __restrict__ dval) {
    const int wave = threadIdx.x >> 6, lane = threadIdx.x & 63;
    const int r = blockIdx.x * 4 + wave;
    const int b = r >> 12;
    const float* xr = x + (size_t)r * CC;
    const double* gb = gbuf + (size_t)b * CC;
    ushort* oh = xh + (size_t)r * KP;
    ushort* ol = xl + (size_t)r * KP;
    float ss = 0.f;
    double d = 0.0;
#pragma unroll
    for (int k = 0; k < 3; k++) {
        const int c = lane + k * 64;
        if (c < 144) {
            float4 v = make_float4(0.f, 0.f, 0.f, 0.f);
            if (c < 138) {
                v = reinterpret_cast<const float4*>(xr)[c];
                ss += v.x * v.x + v.y * v.y + v.z * v.z + v.w * v.w;
                const double* gp = gb + c * 4;
                d += (double)v.x * gp[0] + (double)v.y * gp[1] +
                     (double)v.z * gp[2] + (double)v.w * gp[3];
            }
            ushort4 h, l;
            h.x = f2bf(v.x); l.x = f2bf(v.x - bf2f(h.x));
            h.y = f2bf(v.y); l.y = f2bf(v.y - bf2f(h.y));
            h.z = f2bf(v.z); l.z = f2bf(v.z - bf2f(h.z));
            h.w = f2bf(v.w); l.w = f2bf(v.w - bf2f(h.w));
            reinterpret_cast<ushort4*>(oh)[c] = h;
            reinterpret_cast<ushort4*>(ol)[c] = l;
        }
    }
#pragma unroll
    for (int o = 32; o > 0; o >>= 1) { ss += __shfl_down(ss, o, 64); d += __shfl_down(d, o, 64); }
    if (lane == 0) {
        inv[r] = 1.f / (sqrtf(ss / (float)CC) + 1e-6f);
        dval[r] = d;
    }
}

// ---------- device bodies for fused weight conversions ----------
__device__ __forceinline__ void conv_row_kp_hi(const float* __restrict__ src, int n, int nvalid,
                                               ushort* __restrict__ wh, int t) {
    if (t >= 144) return;
    float4 v = make_float4(0.f, 0.f, 0.f, 0.f);
    if (n < nvalid && t < 138) v = reinterpret_cast<const float4*>(src + (size_t)n * CC)[t];
    ushort4 h;
    h.x = f2bf(v.x); h.y = f2bf(v.y); h.z = f2bf(v.z); h.w = f2bf(v.w);
    reinterpret_cast<ushort4*>(wh + (size_t)n * KP)[t] = h;
}

__device__ __forceinline__ void conv_row_kp2_hi(const float* __restrict__ src, int n,
                                                ushort* __restrict__ wh, int t) {
    for (int i = t; i < KP2 / 4; i += 256) {
        float4 v = make_float4(0.f, 0.f, 0.f, 0.f);
        if (n < CC && i < EE / 4) v = reinterpret_cast<const float4*>(src + (size_t)n * EE)[i];
        ushort4 h;
        h.x = f2bf(v.x); h.y = f2bf(v.y); h.z = f2bf(v.z); h.w = f2bf(v.w);
        reinterpret_cast<ushort4*>(wh + (size_t)n * KP2)[i] = h;
    }
}

__device__ __forceinline__ void conv_row_kp2_full(const float* __restrict__ src, int n,
                                                  ushort* __restrict__ wh, ushort* __restrict__ wl, int t) {
    for (int i = t; i < KP2 / 4; i += 256) {
        float4 v = make_float4(0.f, 0.f, 0.f, 0.f);
        if (n < CC && i < EE / 4) v = reinterpret_cast<const float4*>(src + (size_t)n * EE)[i];
        ushort4 h, l;
        h.x = f2bf(v.x); l.x = f2bf(v.x - bf2f(h.x));
        h.y = f2bf(v.y); l.y = f2bf(v.y - bf2f(h.y));
        h.z = f2bf(v.z); l.z = f2bf(v.z - bf2f(h.z));
        h.w = f2bf(v.w); l.w = f2bf(v.w - bf2f(h.w));
        reinterpret_cast<ushort4*>(wh + (size_t)n * KP2)[i] = h;
        reinterpret_cast<ushort4*>(wl + (size_t)n * KP2)[i] = l;
    }
}

__device__ void taps19_body(const float* __restrict__ A, const float* __restrict__ Bp,
                            const float* __restrict__ Cp, const float* __restrict__ conv_w,
                            float* __restrict__ ck19, int t) {
    __shared__ float Ash[256];
    __shared__ float vmat[JT][16];
    Ash[t] = A[t];
    __syncthreads();
    if (t < 16) vmat[0][t] = 1.f / (1.f + expf(-Bp[t]));
    __syncthreads();
    for (int j = 1; j < JT; j++) {
        float nv = 0.f;
        if (t < 16) {
#pragma unroll
            for (int s2 = 0; s2 < 16; s2++) nv += Ash[t * 16 + s2] * vmat[j - 1][s2];
        }
        __syncthreads();
        if (t < 16) vmat[j][t] = nv;
        __syncthreads();
    }
    for (int e = t; e < EE; e += 256) {
        float sc[16];
#pragma unroll
        for (int s = 0; s < 16; s++) sc[s] = 1.f / (1.f + expf(-Cp[e * 16 + s]));
        float ck[JT];
#pragma unroll
        for (int j = 0; j < JT; j++) {
            float kk = 0.f;
#pragma unroll
            for (int s = 0; s < 16; s++) kk += sc[s] * vmat[j][s];
            ck[j] = kk;
        }
        float w4[4];
#pragma unroll
        for (int i = 0; i < 4; i++) w4[i] = conv_w[e * 4 + 3 - i];
#pragma unroll
        for (int m = 0; m < JC; m++) {
            float kk = 0.f;
#pragma unroll
            for (int i = 0; i < 4; i++) {
                int jm = m - i;
                if (jm >= 0 && jm < JT) kk += w4[i] * ck[jm];
            }
            ck19[m * EE + e] = kk;
        }
    }
}

// ---------- fused weight conversions + taps ----------
__global__ __launch_bounds__(256) void wconv_fused(
    const float* __restrict__ winp, const float* __restrict__ w_out,
    const float* __restrict__ winpT,
    const float* __restrict__ A, const float* __restrict__ Bp,
    const float* __restrict__ Cp, const float* __restrict__ conv_w,
    ushort* __restrict__ wh,
    ushort* __restrict__ w2h,
    ushort* __restrict__ wth, ushort* __restrict__ wtl,
    float* __restrict__ ck19) {
    int bx = blockIdx.x;
    const int t = threadIdx.x;
    if (bx < 1152) { conv_row_kp_hi(winp, bx, EE, wh, t); return; }
    bx -= 1152;
    if (bx < 640) { conv_row_kp2_hi(w_out, bx, w2h, t); return; }
    bx -= 640;
    if (bx < 640) { conv_row_kp2_full(winpT, bx, wth, wtl, t); return; }
    taps19_body(A, Bp, Cp, conv_w, ck19, t);
}

// ---------- triangular-masked conversion of G (sums split-K partials) ----------
__global__ __launch_bounds__(256) void convG_kernel(const float* __restrict__ Gp,
                                                    ushort* __restrict__ gh, ushort* __restrict__ gl) {
    const int n = blockIdx.x, t = threadIdx.x;
    if (t >= 144) return;
    float4 v = make_float4(0.f, 0.f, 0.f, 0.f);
    if (n < CC && t < 138) {
#pragma unroll
        for (int c = 0; c < 5; c++) {
            float4 p = reinterpret_cast<const float4*>(Gp + (size_t)c * 640 * CC + (size_t)n * CC)[t];
            v = make_float4(v.x + p.x, v.y + p.y, v.z + p.z, v.w + p.w);
        }
        const int k0 = t * 4;
        float m0 = (n > k0 + 0) ? 2.f : (n == k0 + 0) ? 1.f : 0.f;
        float m1 = (n > k0 + 1) ? 2.f : (n == k0 + 1) ? 1.f : 0.f;
        float m2 = (n > k0 + 2) ? 2.f : (n == k0 + 2) ? 1.f : 0.f;
        float m3 = (n > k0 + 3) ? 2.f : (n == k0 + 3) ? 1.f : 0.f;
        v = make_float4(v.x * m0, v.y * m1, v.z * m2, v.w * m3);
    }
    ushort4 h, l;
    h.x = f2bf(v.x); l.x = f2bf(v.x - bf2f(h.x));
    h.y = f2bf(v.y); l.y = f2bf(v.y - bf2f(h.y));
    h.z = f2bf(v.z); l.z = f2bf(v.z - bf2f(h.z));
    h.w = f2bf(v.w); l.w = f2bf(v.w - bf2f(h.w));
    reinterpret_cast<ushort4*>(gh + (size_t)n * KP)[t] = h;
    reinterpret_cast<ushort4*>(gl + (size_t)n * KP)[t] = l;
}

// ---------- gemmG: G-partial[z] = W[:,kz:kz+224] @ W[:,kz:kz+224]^T (3-product split-bf16) ----------
__global__ __launch_bounds__(256) void gemmG_kernel(
    const ushort* __restrict__ Wh, const ushort* __restrict__ Wl,   // [640][KP2]
    float* __restrict__ Gp) {
    __shared__ ushort As_h[2][128][32];
    __shared__ ushort As_l[2][128][32];
    __shared__ ushort Bs_h[2][128][32];
    __shared__ ushort Bs_l[2][128][32];
    const int tid = threadIdx.x;
    const int col0 = blockIdx.x * 128;
    const int row0 = blockIdx.y * 128;
    const int kbeg = blockIdx.z * GKC;
    const int kend = kbeg + GKC;
    const int wave = tid >> 6, lane = tid & 63;
    const int wr = (wave >> 1) * 64, wc = (wave & 1) * 64;
    const int lrow = lane & 15, kb = (lane >> 4) * 8;

    const int s0 = wave * 32 + (lane >> 2);
    const int skh = (lane & 3) * 8;
    const ushort* gAh0 = Wh + (size_t)(row0 + s0) * KP2 + skh;
    const ushort* gAl0 = Wl + (size_t)(row0 + s0) * KP2 + skh;
    const ushort* gBh0 = Wh + (size_t)(col0 + s0) * KP2 + skh;
    const ushort* gBl0 = Wl + (size_t)(col0 + s0) * KP2 + skh;
    const size_t rstep = (size_t)16 * KP2;

    f32x4 acc[4][4];
    const f32x4 zero = {0.f, 0.f, 0.f, 0.f};
#pragma unroll
    for (int i = 0; i < 4; i++)
#pragma unroll
        for (int j = 0; j < 4; j++) acc[i][j] = zero;

    auto stage = [&](int buf, int k0) {
        gl_lds16(gAh0 + k0, &As_h[buf][wave * 32][0]);
        gl_lds16(gAh0 + rstep + k0, &As_h[buf][wave * 32 + 16][0]);
        gl_lds16(gAl0 + k0, &As_l[buf][wave * 32][0]);
        gl_lds16(gAl0 + rstep + k0, &As_l[buf][wave * 32 + 16][0]);
        gl_lds16(gBh0 + k0, &Bs_h[buf][wave * 32][0]);
        gl_lds16(gBh0 + rstep + k0, &Bs_h[buf][wave * 32 + 16][0]);
        gl_lds16(gBl0 + k0, &Bs_l[buf][wave * 32][0]);
        gl_lds16(gBl0 + rstep + k0, &Bs_l[buf][wave * 32 + 16][0]);
    };
    auto compute = [&](int buf) {
        bf16x8 ah[4], al[4], bh[4], bl[4];
#pragma unroll
        for (int i = 0; i < 4; i++) {
            ah[i] = *reinterpret_cast<const bf16x8*>(&As_h[buf][wr + i * 16 + lrow][kb]);
            al[i] = *reinterpret_cast<const bf16x8*>(&As_l[buf][wr + i * 16 + lrow][kb]);
            bh[i] = *reinterpret_cast<const bf16x8*>(&Bs_h[buf][wc + i * 16 + lrow][kb]);
            bl[i] = *reinterpret_cast<const bf16x8*>(&Bs_l[buf][wc + i * 16 + lrow][kb]);
        }
#pragma unroll
        for (int i = 0; i < 4; i++)
#pragma unroll
            for (int j = 0; j < 4; j++) {
                acc[i][j] = __builtin_amdgcn_mfma_f32_16x16x32_bf16(ah[i], bh[j], acc[i][j], 0, 0, 0);
                acc[i][j] = __builtin_amdgcn_mfma_f32_16x16x32_bf16(ah[i], bl[j], acc[i][j], 0, 0, 0);
                acc[i][j] = __builtin_amdgcn_mfma_f32_16x16x32_bf16(al[i], bh[j], acc[i][j], 0, 0, 0);
            }
    };

    stage(0, kbeg);
    __syncthreads();
    int cur = 0;
    for (int k0 = kbeg + 32; k0 < kend; k0 += 32) {
        stage(cur ^ 1, k0);
        compute(cur);
        __syncthreads();
        cur ^= 1;
    }
    compute(cur);

    float* Gc = Gp + (size_t)blockIdx.z * 640 * CC;
#pragma unroll
    for (int i = 0; i < 4; i++) {
        const int gmb = row0 + wr + i * 16 + (lane >> 4) * 4;
#pragma unroll
        for (int reg = 0; reg < 4; reg++) {
            const int gm = gmb + reg;
            if (gm < CC) {
#pragma unroll
                for (int j = 0; j < 4; j++) {
                    const int gn = col0 + wc + j * 16 + lrow;
                    if (gn < CC) Gc[(size_t)gm * CC + gn] = acc[i][j][reg];
                }
            }
        }
    }
}

// ---------- single-product bf16 GEMM (selected path; 2-phase prefetch) ----------
__global__ __launch_bounds__(256) void gemm_mfma_1x(
    const ushort* __restrict__ Ah,     // [Mp][Kp] bf16
    const ushort* __restrict__ Bh,     // [Np][Kp] bf16
    const float* __restrict__ rowscale, const float* __restrict__ bias,
    float* __restrict__ C, int ldc, int M, int N, int Kp, int r0) {
    __shared__ ushort As[2][128][32];
    __shared__ ushort Bs[2][128][32];
    const int tid = threadIdx.x;
    const int col0 = blockIdx.x * 128;
    const int row0 = blockIdx.y * 128;
    const int wave = tid >> 6, lane = tid & 63;
    const int wr = (wave >> 1) * 64, wc = (wave & 1) * 64;
    const int lrow = lane & 15, kb = (lane >> 4) * 8;

    const int s0 = wave * 32 + (lane >> 2);
    const int skh = (lane & 3) * 8;
    const ushort* gA0 = Ah + (size_t)(row0 + s0) * Kp + skh;
    const ushort* gB0 = Bh + (size_t)(col0 + s0) * Kp + skh;
    const size_t rstep = (size_t)16 * Kp;

    f32x4 acc[4][4];
    const f32x4 zero = {0.f, 0.f, 0.f, 0.f};
#pragma unroll
    for (int i = 0; i < 4; i++)
#pragma unroll
        for (int j = 0; j < 4; j++) acc[i][j] = zero;

    auto stage = [&](int buf, int k0) {
        gl_lds16(gA0 + k0, &As[buf][wave * 32][0]);
        gl_lds16(gA0 + rstep + k0, &As[buf][wave * 32 + 16][0]);
        gl_lds16(gB0 + k0, &Bs[buf][wave * 32][0]);
        gl_lds16(gB0 + rstep + k0, &Bs[buf][wave * 32 + 16][0]);
    };
    auto compute = [&](int buf) {
        bf16x8 ah[4], bh[4];
#pragma unroll
        for (int i = 0; i < 4; i++) {
            ah[i] = *reinterpret_cast<const bf16x8*>(&As[buf][wr + i * 16 + lrow][kb]);
            bh[i] = *reinterpret_cast<const bf16x8*>(&Bs[buf][wc + i * 16 + lrow][kb]);
        }
#pragma unroll
        for (int i = 0; i < 4; i++)
#pragma unroll
            for (int j = 0; j < 4; j++)
                acc[i][j] = __builtin_amdgcn_mfma_f32_16x16x32_bf16(ah[i], bh[j], acc[i][j], 0, 0, 0);
    };

    stage(0, 0);
    __syncthreads();
    int cur = 0;
    for (int k0 = 32; k0 < Kp; k0 += 32) {
        stage(cur ^ 1, k0);
        compute(cur);
        __syncthreads();
        cur ^= 1;
    }
    compute(cur);

#pragma unroll
    for (int i = 0; i < 4; i++) {
        const int gmb = r0 + row0 + wr + i * 16 + (lane >> 4) * 4;
#pragma unroll
        for (int reg = 0; reg < 4; reg++) {
            const int gm = gmb + reg;
            if (gm < M) {
                const float rs = rowscale ? rowscale[gm] : 1.f;
#pragma unroll
                for (int j = 0; j < 4; j++) {
                    const int gn = col0 + wc + j * 16 + lrow;
                    if (gn < N) C[(size_t)gm * ldc + gn] = acc[i][j][reg] * rs + (bias ? bias[gn] : 0.f);
                }
            }
        }
    }
}

// ---------- gemmq: XCD-swizzled, SINGLE-buffer LDS (4 blk/CU), triangular kend ----------
// epilogue weights from xh+xl (bf16, L2-hot) instead of fp32 x stream.
__global__ __launch_bounds__(256) void gemm_mfma_q(
    const ushort* __restrict__ Ah, const ushort* __restrict__ Al,   // x hi/lo [M1][KP]
    const ushort* __restrict__ Bh, const ushort* __restrict__ Bl,   // Ghat hi/lo [640][KP]
    float* __restrict__ qpart) {
    __shared__ ushort As_h[128][32];
    __shared__ ushort As_l[128][32];
    __shared__ ushort Bs_h[128][32];
    __shared__ ushort Bs_l[128][32];
    const int tid = threadIdx.x;
    // bijective XCD swizzle (m204): nwg=1280, 160/XCD; co-locates the 5 col-tiles
    // of each row-tile on one XCD so their shared A k-tiles become L2 hits [T1].
    const int orig = blockIdx.x;
    const int work = (orig & 7) * 160 + (orig >> 3);
    const int ct = work % NQT;          // col tile
    const int rt = work / NQT;          // row tile
    const int col0 = ct * 128;
    const int row0 = rt * 128;
    const int kend = (KP < col0 + 128) ? KP : (col0 + 128);   // triangular cut
    const int wave = tid >> 6, lane = tid & 63;
    const int wr = (wave >> 1) * 64, wc = (wave & 1) * 64;
    const int lrow = lane & 15, kb = (lane >> 4) * 8;

    const int s0 = wave * 32 + (lane >> 2);
    const int skh = (lane & 3) * 8;
    const ushort* gAh0 = Ah + (size_t)(row0 + s0) * KP + skh;
    const ushort* gAl0 = Al + (size_t)(row0 + s0) * KP + skh;
    const ushort* gBh0 = Bh + (size_t)(col0 + s0) * KP + skh;
    const ushort* gBl0 = Bl + (size_t)(col0 + s0) * KP + skh;
    const size_t rstep = (size_t)16 * KP;
    ushort* lAh0 = &As_h[wave * 32][0];      ushort* lAh1 = &As_h[wave * 32 + 16][0];
    ushort* lAl0 = &As_l[wave * 32][0];      ushort* lAl1 = &As_l[wave * 32 + 16][0];
    ushort* lBh0 = &Bs_h[wave * 32][0];      ushort* lBh1 = &Bs_h[wave * 32 + 16][0];
    ushort* lBl0 = &Bs_l[wave * 32][0];      ushort* lBl1 = &Bs_l[wave * 32 + 16][0];

    f32x4 acc[4][4];
    const f32x4 zero = {0.f, 0.f, 0.f, 0.f};
#pragma unroll
    for (int i = 0; i < 4; i++)
#pragma unroll
        for (int j = 0; j < 4; j++) acc[i][j] = zero;

    for (int k0 = 0; k0 < kend; k0 += 32) {
        __syncthreads();
        gl_lds16(gAh0 + k0, lAh0); gl_lds16(gAh0 + rstep + k0, lAh1);
        gl_lds16(gAl0 + k0, lAl0); gl_lds16(gAl0 + rstep + k0, lAl1);
        gl_lds16(gBh0 + k0, lBh0); gl_lds16(gBh0 + rstep + k0, lBh1);
        gl_lds16(gBl0 + k0, lBl0); gl_lds16(gBl0 + rstep + k0, lBl1);
        __syncthreads();
        bf16x8 ah[4], al[4], bh[4], bl[4];
#pragma unroll
        for (int i = 0; i < 4; i++) {
            ah[i] = *reinterpret_cast<const bf16x8*>(&As_h[wr + i * 16 + lrow][kb]);
            al[i] = *reinterpret_cast<const bf16x8*>(&As_l[wr + i * 16 + lrow][kb]);
            bh[i] = *reinterpret_cast<const bf16x8*>(&Bs_h[wc + i * 16 + lrow][kb]);
            bl[i] = *reinterpret_cast<const bf16x8*>(&Bs_l[wc + i * 16 + lrow][kb]);
        }
#pragma unroll
        for (int i = 0; i < 4; i++)
#pragma unroll
            for (int j = 0; j < 4; j++) {
                acc[i][j] = __builtin_amdgcn_mfma_f32_16x16x32_bf16(ah[i], bh[j], acc[i][j], 0, 0, 0);
                acc[i][j] = __builtin_amdgcn_mfma_f32_16x16x32_bf16(ah[i], bl[j], acc[i][j], 0, 0, 0);
                acc[i][j] = __builtin_amdgcn_mfma_f32_16x16x32_bf16(al[i], bh[j], acc[i][j], 0, 0, 0);
            }
    }

    float* qp = qpart + (size_t)ct * M1;
#pragma unroll
    for (int i = 0; i < 4; i++) {
#pragma unroll
        for (int reg = 0; reg < 4; reg++) {
            const int gm = row0 + wr + i * 16 + (lane >> 4) * 4 + reg;
            float part = 0.f;
#pragma unroll
            for (int j = 0; j < 4; j++) {
                const int gn = col0 + wc + j * 16 + lrow;
                float xv = 0.f;
                if (gn < CC) {
                    const size_t o = (size_t)gm * KP + gn;
                    xv = bf2f(Ah[o]) + bf2f(Al[o]);   // x to ~2^-17 rel; L2-hot (just streamed)
                }
                part += acc[i][j][reg] * xv;
            }
#pragma unroll
            for (int o = 1; o < 16; o <<= 1) part += __shfl_xor(part, o, 64);
            if ((lane & 15) == 0) atomicAdd(&qp[gm], part);  // 2 commutative adds/cell: deterministic
        }
    }
}

// ---------- center row -> fp64 normalized (one block per batch) ----------
__global__ __launch_bounds__(256) void center_kernel(const float* __restrict__ x,
                                                     double* __restrict__ xcn) {
    __shared__ double red[4];
    const int b = blockIdx.x, tid = threadIdx.x;
    const float* xc = x + ((size_t)(b * LL + LL / 2)) * CC;
    double s = 0.0;
    for (int c = tid; c < CC; c += 256) { double v = xc[c]; s += v * v; }
#pragma unroll
    for (int o = 32; o > 0; o >>= 1) s += __shfl_down(s, o, 64);
    if ((tid & 63) == 0) red[tid >> 6] = s;
    __syncthreads();
    const double tot = red[0] + red[1] + red[2] + red[3];
    const double invc = 1.0 / (sqrt(tot / (double)CC) + 1e-6);
    for (int c = tid; c < CC; c += 256) xcn[(size_t)b * CC + c] = (double)xc[c] * invc;
}

// ---------- t1[b][e] = <W'_e, xcn_b>, one wave per (b,e) ----------
__global__ __launch_bounds__(256) void gram1_kernel(const float* __restrict__ winp,
                                                    const double* __restrict__ xcn,
                                                    double* __restrict__ t1) {
    const int b = blockIdx.y;
    const int wave = threadIdx.x >> 6, lane = threadIdx.x & 63;
    const int e = blockIdx.x * 4 + wave;
    const float* wr = winp + (size_t)e * CC;
    const double* xb = xcn + (size_t)b * CC;
    double s = 0.0;
    for (int c = lane; c < CC; c += 64) s += (double)wr[c] * xb[c];
#pragma unroll
    for (int o = 32; o > 0; o >>= 1) s += __shfl_down(s, o, 64);
    if (lane == 0) t1[(size_t)b * EE + e] = s;
}

// ---------- g[b][c] = <W'T_c, t1_b>, one wave per (b,c) ----------
__global__ __launch_bounds__(256) void gram2_kernel(const float* __restrict__ winpT,
                                                    const double* __restrict__ t1,
                                                    double* __restrict__ g) {
    const int b = blockIdx.y;
    const int wave = threadIdx.x >> 6, lane = threadIdx.x & 63;
    const int c = blockIdx.x * 4 + wave;
    if (c >= CC) return;
    const float* wr = winpT + (size_t)c * EE;
    const double* tb = t1 + (size_t)b * EE;
    double s = 0.0;
    for (int e = lane; e < EE; e += 64) s += (double)wr[e] * tb[e];
#pragma unroll
    for (int o = 32; o > 0; o >>= 1) s += __shfl_down(s, o, 64);
    if (lane == 0) g[(size_t)b * CC + c] = s;
}

// ---------- top-k; sim computed inline: sim = dval / sqrt(sum qpart) ----------
__global__ __launch_bounds__(1024) void topk_kernel(const double* __restrict__ dval,
                                                    const float* __restrict__ qpart,
                                                    int* __restrict__ idx) {
    __shared__ unsigned long long keys[4096];
    const int b = blockIdx.x;
    for (int i = threadIdx.x; i < 4096; i += 1024) {
        const int r = b * 4096 + i;
        double q = 0.0;
#pragma unroll
        for (int t5 = 0; t5 < NQT; t5++) q += (double)qpart[(size_t)t5 * M1 + r];
        const float sv = (float)(dval[r] / sqrt(fmax(q, 1e-30)));
        unsigned u = __float_as_uint(sv);
        u = (u & 0x80000000u) ? ~u : (u | 0x80000000u);
        keys[i] = ((unsigned long long)(~u) << 32) | (unsigned)i;
    }
    __syncthreads();
    for (int size = 2; size <= 4096; size <<= 1) {
        for (int stride = size >> 1; stride > 0; stride >>= 1) {
#pragma unroll 1
            for (int t = threadIdx.x; t < 2048; t += 1024) {
                int low = t & (stride - 1);
                int pos = ((t - low) << 1) + low;
                bool up = ((pos & size) == 0);
                unsigned long long ka = keys[pos], kb = keys[pos + stride];
                if ((ka > kb) == up) { keys[pos] = kb; keys[pos + stride] = ka; }
            }
            __syncthreads();
        }
    }
    for (int t = threadIdx.x; t < KT; t += 1024) idx[b * KT + t] = (int)(keys[t] & 0xffffffffu);
}

// ---------- gather selected x rows (hi only) + inv; rows >= M2 zeroed; pos map ----------
__global__ __launch_bounds__(256) void gatherx_kernel(const ushort* __restrict__ xh,
                                                      const float* __restrict__ inv,
                                                      const int* __restrict__ idx,
                                                      ushort* __restrict__ sh,
                                                      float* __restrict__ invsel,
                                                      int* __restrict__ pos) {
    const int r = blockIdx.x, t = threadIdx.x;
    if (r >= M2) {
        if (t < 144) reinterpret_cast<ushort4*>(sh + (size_t)r * KP)[t] = make_ushort4(0, 0, 0, 0);
        return;
    }
    const int b = r / KT;
    const int src = b * LL + idx[r];
    if (t < 144) {
        reinterpret_cast<ushort4*>(sh + (size_t)r * KP)[t] =
            reinterpret_cast<const ushort4*>(xh + (size_t)src * KP)[t];
    }
    if (t == 0) {
        invsel[r] = inv[src];
        pos[src] = r;   // reverse map for fused output
    }
}

// ---------- 19-tap causal depthwise conv on selected rows -> bf16 (hi only) for GEMM2 ----------
__global__ __launch_bounds__(256) void conv19_kernel(const float* __restrict__ xps,
                                                     const float* __restrict__ ck19,
                                                     ushort* __restrict__ oh) {
    const int r = blockIdx.x, t = threadIdx.x;
    ushort* ph = oh + (size_t)r * KP2;
    if (r >= M2) {
        for (int e = t; e < KP2; e += 256) ph[e] = 0;
        return;
    }
    const int b = r / KT, tt = r - b * KT;
    const int jmax = (tt < JC - 1) ? tt : (JC - 1);
    const float* base = xps + (size_t)r * EE;
    for (int e = t; e < KP2; e += 256) {
        float y = 0.f;
        if (e < EE) {
            const float* bp = base + e;
            for (int j = 0; j <= jmax; j++) y += ck19[j * EE + e] * bp[-(ptrdiff_t)j * EE];
        }
        ph[e] = f2bf(y);
    }
}

// ---------- fused output: out[r] = x[r] + (pos[r]>=0 ? xproc[pos[r]] : 0), wave-per-row ----------
__global__ __launch_bounds__(256) void outfuse_kernel(const float* __restrict__ x,
                                                      const float* __restrict__ xproc,
                                                      const int* __restrict__ pos,
                                                      float* __restrict__ out) {
    const int wave = threadIdx.x >> 6, lane = threadIdx.x & 63;
    const int r = blockIdx.x * 4 + wave;
    const int p = pos[r];
    const float4* xr = reinterpret_cast<const float4*>(x + (size_t)r * CC);
    float4* orow = reinterpret_cast<float4*>(out + (size_t)r * CC);
    const float4* pr = (p >= 0) ? reinterpret_cast<const float4*>(xproc + (size_t)p * CC) : nullptr;
#pragma unroll
    for (int k = 0; k < 3; k++) {
        const int c = lane + k * 64;
        if (c < 138) {
            float4 v = xr[c];
            if (pr) {
                float4 a = pr[c];
                v = make_float4(v.x + a.x, v.y + a.y, v.z + a.z, v.w + a.w);
            }
            orow[c] = v;
        }
    }
}

extern "C" void kernel_launch(void* const* d_in, const int* in_sizes, int n_in,
                              void* d_out, int out_size, void* d_ws, size_t ws_size,
                              hipStream_t stream) {
    const float* x      = (const float*)d_in[0];
    const float* norm_w = (const float*)d_in[1];
    const float* w_in   = (const float*)d_in[2];
    const float* b_in   = (const float*)d_in[3];
    const float* w_out  = (const float*)d_in[4];
    const float* b_out  = (const float*)d_in[5];
    const float* Amat   = (const float*)d_in[6];
    const float* Bp     = (const float*)d_in[7];
    const float* Cp     = (const float*)d_in[8];
    const float* conv_w = (const float*)d_in[9];
    float* out = (float*)d_out;

    char* wsb = (char*)d_ws;
    size_t off = 0;
    auto take = [&](size_t bytes) {
        void* p = wsb + off;
        off += (bytes + 255) & ~(size_t)255;
        return p;
    };
    ushort* xh    = (ushort*)take((size_t)M1 * KP * 2);       // 37.7 MB
    ushort* xl    = (ushort*)take((size_t)M1 * KP * 2);       // 37.7 MB
    float*  winp  = (float*)take((size_t)EE * CC * 4);
    float*  winpT = (float*)take((size_t)EE * CC * 4);
    ushort* wh    = (ushort*)take((size_t)1152 * KP * 2);
    ushort* w2h   = (ushort*)take((size_t)640 * KP2 * 2);
    ushort* wth   = (ushort*)take((size_t)640 * KP2 * 2);
    ushort* wtl   = (ushort*)take((size_t)640 * KP2 * 2);
    float*  Gp    = (float*)take((size_t)5 * 640 * CC * 4);   // 5 split-K partials
    ushort* Gh    = (ushort*)take((size_t)640 * KP * 2);
    ushort* Gl    = (ushort*)take((size_t)640 * KP * 2);
    float*  inv   = (float*)take((size_t)M1 * 4);
    float*  qpart = (float*)take((size_t)NQT * M1 * 4);
    double* dval  = (double*)take((size_t)M1 * 8);
    int*    posm  = (int*)take((size_t)M1 * 4);
    int*    idxb  = (int*)take((size_t)BB * KT * 4);
    double* gbuf  = (double*)take((size_t)BB * CC * 8);
    double* xcn   = (double*)take((size_t)BB * CC * 8);
    double* t1b   = (double*)take((size_t)BB * EE * 8);
    float*  ck19  = (float*)take((size_t)JC * EE * 4);
    ushort* sh    = (ushort*)take((size_t)M2P * KP * 2);
    float*  invsel= (float*)take((size_t)M2P * 4);
    float*  xps   = (float*)take((size_t)M2P * EE * 4);
    ushort* o2h   = (ushort*)take((size_t)M2P * KP2 * 2);
    float*  xproc = (float*)take((size_t)M2P * CC * 4);
    (void)ws_size;

    // --- fused prep: qpart=0, posm=-1, winp/winpT ---
    prep_kernel<<<(EE * CC + 255) / 256, 256, 0, stream>>>(w_in, norm_w, winp, winpT, qpart, posm);

    // --- gram chain (g_b ready before convx) ---
    center_kernel<<<BB, 256, 0, stream>>>(x, xcn);
    dim3 gg1(EE / 4, BB);
    gram1_kernel<<<gg1, 256, 0, stream>>>(winp, xcn, t1b);
    dim3 gg2(CC / 4, BB);
    gram2_kernel<<<gg2, 256, 0, stream>>>(winpT, t1b, gbuf);

    // --- fused weight conversions + taps ---
    wconv_fused<<<1152 + 640 + 640 + 1, 256, 0, stream>>>(
        winp, w_out, winpT, Amat, Bp, Cp, conv_w, wh, w2h, wth, wtl, ck19);

    // --- convx: bf16 split + inv + fused fp64 numerator dot ---
    convx_kernel<<<M1 / 4, 256, 0, stream>>>(x, gbuf, xh, xl, inv, dval);

    // --- G = W'^T W' (split-K x5, 3-product), masked-summed into Ghat ---
    dim3 gG(5, 5, 5);
    gemmG_kernel<<<gG, 256, 0, stream>>>(wth, wtl, Gp);
    convG_kernel<<<640, 256, 0, stream>>>(Gp, Gh, Gl);

    // --- q_r = x_r^T G x_r via masked Ghat (XCD-swizzled, single-buffer) ---
    gemm_mfma_q<<<NQT * (M1 / 128), 256, 0, stream>>>(xh, xl, Gh, Gl, qpart);

    // --- topk (sim computed inline from dval/qpart) ---
    topk_kernel<<<BB, 1024, 0, stream>>>(dval, qpart, idxb);

    // --- selected rows only: xproj_sel = inv*(x_sel@W'^T) + b_in (bf16-single) ---
    gatherx_kernel<<<M2P, 256, 0, stream>>>(xh, inv, idxb, sh, invsel, posm);
    dim3 g1(9, M2P / 128);
    gemm_mfma_1x<<<g1, 256, 0, stream>>>(sh, wh, invsel, b_in, xps,
                                         EE, M2, EE, KP, 0);

    // --- conv4 ∘ ssm16 = single 19-tap depthwise causal conv (hi-only out) ---
    conv19_kernel<<<M2P, 256, 0, stream>>>(xps, ck19, o2h);

    // --- gemm2 (bf16-single) ---
    dim3 g3(5, M2P / 128);
    gemm_mfma_1x<<<g3, 256, 0, stream>>>(o2h, w2h, nullptr, b_out, xproc,
                                         CC, M2, CC, KP2, 0);

    // --- fused output: out = x (+ xproc on selected rows) ---
    outfuse_kernel<<<M1 / 4, 256, 0, stream>>>(x, xproc, posm, out);
}

// Round 13
// 320.659 us; speedup vs baseline: 1.4290x; 1.1409x over previous
//
#include <hip/hip_runtime.h>
#include <hip/hip_bf16.h>

// Problem constants (fixed by reference)
#define BB 8
#define LL 4096
#define CC 552      // DIM
#define EE 1104     // EXP
#define KT 409      // top-k
#define M1 32768    // B*L
#define M2 3272     // B*KT
#define KP 576      // K padded (gemm over DIM)
#define KP2 1120    // K padded (gemm over EXP)
#define M2P 3328    // M2 padded to 26*128
#define JT 16       // SSM truncation taps (||A||^16 ~ 2e-13)
#define JC 19       // composed conv4 * ssm16 taps
#define NQT 5       // col tiles in gemmq (640/128)
#define GKC 224     // gemmG K-chunk (1120/5)
#define NCB ((EE * CC + 255) / 256)   // elementwise blocks in prep

typedef __attribute__((ext_vector_type(8))) short bf16x8;
typedef __attribute__((ext_vector_type(4))) float f32x4;

__device__ __forceinline__ ushort f2bf(float f) {
    unsigned u = __float_as_uint(f);
    return (ushort)((u + 0x7FFFu + ((u >> 16) & 1u)) >> 16);  // RNE
}
__device__ __forceinline__ float bf2f(ushort h) {
    return __uint_as_float(((unsigned)h) << 16);
}

// async global->LDS, 16B per lane; LDS dest = wave-uniform base + lane*16 [m97/m03]
__device__ __forceinline__ void gl_lds16(const ushort* g, ushort* l) {
    __builtin_amdgcn_global_load_lds(
        (const __attribute__((address_space(1))) void*)g,
        (__attribute__((address_space(3))) void*)l, 16, 0, 0);
}

// ---------- fused prep: qpart=0, posm=-1, winp/winpT, center rows -> fp64 normalized ----------
__global__ __launch_bounds__(256) void prep_kernel(const float* __restrict__ w_in,
                                                   const float* __restrict__ norm_w,
                                                   const float* __restrict__ x,
                                                   float* __restrict__ winp, float* __restrict__ winpT,
                                                   float* __restrict__ qpart, int* __restrict__ posm,
                                                   double* __restrict__ xcn) {
    const int bx = blockIdx.x;
    if (bx < NCB) {
        int i = bx * 256 + threadIdx.x;
        if (i < NQT * M1) qpart[i] = 0.f;
        if (i < M1) posm[i] = -1;
        if (i < EE * CC) {
            int c = i % CC, e = i / CC;
            float v = w_in[i] * norm_w[c];
            winp[i] = v;
            winpT[(size_t)c * EE + e] = v;
        }
        return;
    }
    // center role: one block per batch
    __shared__ double red[4];
    const int b = bx - NCB, tid = threadIdx.x;
    const float* xc = x + ((size_t)(b * LL + LL / 2)) * CC;
    double s = 0.0;
    for (int c = tid; c < CC; c += 256) { double v = xc[c]; s += v * v; }
#pragma unroll
    for (int o = 32; o > 0; o >>= 1) s += __shfl_down(s, o, 64);
    if ((tid & 63) == 0) red[tid >> 6] = s;
    __syncthreads();
    const double tot = red[0] + red[1] + red[2] + red[3];
    const double invc = 1.0 / (sqrt(tot / (double)CC) + 1e-6);
    for (int c = tid; c < CC; c += 256) xcn[(size_t)b * CC + c] = (double)xc[c] * invc;
}

// ---------- convx: wave-per-row; bf16 hi/lo + inv + fp64 dval = <x_r, g_b> ----------
__global__ __launch_bounds__(256) void convx_kernel(const float* __restrict__ x,
                                                    const double* __restrict__ gbuf,
                                                    ushort* __restrict__ xh, ushort* __restrict__ xl,
                                                    float* __restrict__ inv,
                                                    double* __restrict__ dval) {
    const int wave = threadIdx.x >> 6, lane = threadIdx.x & 63;
    const int r = blockIdx.x * 4 + wave;
    const int b = r >> 12;
    const float* xr = x + (size_t)r * CC;
    const double* gb = gbuf + (size_t)b * CC;
    ushort* oh = xh + (size_t)r * KP;
    ushort* ol = xl + (size_t)r * KP;
    float ss = 0.f;
    double d = 0.0;
#pragma unroll
    for (int k = 0; k < 3; k++) {
        const int c = lane + k * 64;
        if (c < 144) {
            float4 v = make_float4(0.f, 0.f, 0.f, 0.f);
            if (c < 138) {
                v = reinterpret_cast<const float4*>(xr)[c];
                ss += v.x * v.x + v.y * v.y + v.z * v.z + v.w * v.w;
                const double* gp = gb + c * 4;
                d += (double)v.x * gp[0] + (double)v.y * gp[1] +
                     (double)v.z * gp[2] + (double)v.w * gp[3];
            }
            ushort4 h, l;
            h.x = f2bf(v.x); l.x = f2bf(v.x - bf2f(h.x));
            h.y = f2bf(v.y); l.y = f2bf(v.y - bf2f(h.y));
            h.z = f2bf(v.z); l.z = f2bf(v.z - bf2f(h.z));
            h.w = f2bf(v.w); l.w = f2bf(v.w - bf2f(h.w));
            reinterpret_cast<ushort4*>(oh)[c] = h;
            reinterpret_cast<ushort4*>(ol)[c] = l;
        }
    }
#pragma unroll
    for (int o = 32; o > 0; o >>= 1) { ss += __shfl_down(ss, o, 64); d += __shfl_down(d, o, 64); }
    if (lane == 0) {
        inv[r] = 1.f / (sqrtf(ss / (float)CC) + 1e-6f);
        dval[r] = d;
    }
}

// ---------- device bodies for fused weight conversions ----------
__device__ __forceinline__ void conv_row_kp_hi(const float* __restrict__ src, int n, int nvalid,
                                               ushort* __restrict__ wh, int t) {
    if (t >= 144) return;
    float4 v = make_float4(0.f, 0.f, 0.f, 0.f);
    if (n < nvalid && t < 138) v = reinterpret_cast<const float4*>(src + (size_t)n * CC)[t];
    ushort4 h;
    h.x = f2bf(v.x); h.y = f2bf(v.y); h.z = f2bf(v.z); h.w = f2bf(v.w);
    reinterpret_cast<ushort4*>(wh + (size_t)n * KP)[t] = h;
}

__device__ __forceinline__ void conv_row_kp2_hi(const float* __restrict__ src, int n,
                                                ushort* __restrict__ wh, int t) {
    for (int i = t; i < KP2 / 4; i += 256) {
        float4 v = make_float4(0.f, 0.f, 0.f, 0.f);
        if (n < CC && i < EE / 4) v = reinterpret_cast<const float4*>(src + (size_t)n * EE)[i];
        ushort4 h;
        h.x = f2bf(v.x); h.y = f2bf(v.y); h.z = f2bf(v.z); h.w = f2bf(v.w);
        reinterpret_cast<ushort4*>(wh + (size_t)n * KP2)[i] = h;
    }
}

__device__ __forceinline__ void conv_row_kp2_full(const float* __restrict__ src, int n,
                                                  ushort* __restrict__ wh, ushort* __restrict__ wl, int t) {
    for (int i = t; i < KP2 / 4; i += 256) {
        float4 v = make_float4(0.f, 0.f, 0.f, 0.f);
        if (n < CC && i < EE / 4) v = reinterpret_cast<const float4*>(src + (size_t)n * EE)[i];
        ushort4 h, l;
        h.x = f2bf(v.x); l.x = f2bf(v.x - bf2f(h.x));
        h.y = f2bf(v.y); l.y = f2bf(v.y - bf2f(h.y));
        h.z = f2bf(v.z); l.z = f2bf(v.z - bf2f(h.z));
        h.w = f2bf(v.w); l.w = f2bf(v.w - bf2f(h.w));
        reinterpret_cast<ushort4*>(wh + (size_t)n * KP2)[i] = h;
        reinterpret_cast<ushort4*>(wl + (size_t)n * KP2)[i] = l;
    }
}

__device__ void taps19_body(const float* __restrict__ A, const float* __restrict__ Bp,
                            const float* __restrict__ Cp, const float* __restrict__ conv_w,
                            float* __restrict__ ck19, int t) {
    __shared__ float Ash[256];
    __shared__ float vmat[JT][16];
    Ash[t] = A[t];
    __syncthreads();
    if (t < 16) vmat[0][t] = 1.f / (1.f + expf(-Bp[t]));
    __syncthreads();
    for (int j = 1; j < JT; j++) {
        float nv = 0.f;
        if (t < 16) {
#pragma unroll
            for (int s2 = 0; s2 < 16; s2++) nv += Ash[t * 16 + s2] * vmat[j - 1][s2];
        }
        __syncthreads();
        if (t < 16) vmat[j][t] = nv;
        __syncthreads();
    }
    for (int e = t; e < EE; e += 256) {
        float sc[16];
#pragma unroll
        for (int s = 0; s < 16; s++) sc[s] = 1.f / (1.f + expf(-Cp[e * 16 + s]));
        float ck[JT];
#pragma unroll
        for (int j = 0; j < JT; j++) {
            float kk = 0.f;
#pragma unroll
            for (int s = 0; s < 16; s++) kk += sc[s] * vmat[j][s];
            ck[j] = kk;
        }
        float w4[4];
#pragma unroll
        for (int i = 0; i < 4; i++) w4[i] = conv_w[e * 4 + 3 - i];
#pragma unroll
        for (int m = 0; m < JC; m++) {
            float kk = 0.f;
#pragma unroll
            for (int i = 0; i < 4; i++) {
                int jm = m - i;
                if (jm >= 0 && jm < JT) kk += w4[i] * ck[jm];
            }
            ck19[m * EE + e] = kk;
        }
    }
}

// ---------- fused weight conversions + taps ----------
__global__ __launch_bounds__(256) void wconv_fused(
    const float* __restrict__ winp, const float* __restrict__ w_out,
    const float* __restrict__ winpT,
    const float* __restrict__ A, const float* __restrict__ Bp,
    const float* __restrict__ Cp, const float* __restrict__ conv_w,
    ushort* __restrict__ wh,
    ushort* __restrict__ w2h,
    ushort* __restrict__ wth, ushort* __restrict__ wtl,
    float* __restrict__ ck19) {
    int bx = blockIdx.x;
    const int t = threadIdx.x;
    if (bx < 1152) { conv_row_kp_hi(winp, bx, EE, wh, t); return; }
    bx -= 1152;
    if (bx < 640) { conv_row_kp2_hi(w_out, bx, w2h, t); return; }
    bx -= 640;
    if (bx < 640) { conv_row_kp2_full(winpT, bx, wth, wtl, t); return; }
    taps19_body(A, Bp, Cp, conv_w, ck19, t);
}

// ---------- triangular-masked conversion of G (sums split-K partials) ----------
__global__ __launch_bounds__(256) void convG_kernel(const float* __restrict__ Gp,
                                                    ushort* __restrict__ gh, ushort* __restrict__ gl) {
    const int n = blockIdx.x, t = threadIdx.x;
    if (t >= 144) return;
    float4 v = make_float4(0.f, 0.f, 0.f, 0.f);
    if (n < CC && t < 138) {
#pragma unroll
        for (int c = 0; c < 5; c++) {
            float4 p = reinterpret_cast<const float4*>(Gp + (size_t)c * 640 * CC + (size_t)n * CC)[t];
            v = make_float4(v.x + p.x, v.y + p.y, v.z + p.z, v.w + p.w);
        }
        const int k0 = t * 4;
        float m0 = (n > k0 + 0) ? 2.f : (n == k0 + 0) ? 1.f : 0.f;
        float m1 = (n > k0 + 1) ? 2.f : (n == k0 + 1) ? 1.f : 0.f;
        float m2 = (n > k0 + 2) ? 2.f : (n == k0 + 2) ? 1.f : 0.f;
        float m3 = (n > k0 + 3) ? 2.f : (n == k0 + 3) ? 1.f : 0.f;
        v = make_float4(v.x * m0, v.y * m1, v.z * m2, v.w * m3);
    }
    ushort4 h, l;
    h.x = f2bf(v.x); l.x = f2bf(v.x - bf2f(h.x));
    h.y = f2bf(v.y); l.y = f2bf(v.y - bf2f(h.y));
    h.z = f2bf(v.z); l.z = f2bf(v.z - bf2f(h.z));
    h.w = f2bf(v.w); l.w = f2bf(v.w - bf2f(h.w));
    reinterpret_cast<ushort4*>(gh + (size_t)n * KP)[t] = h;
    reinterpret_cast<ushort4*>(gl + (size_t)n * KP)[t] = l;
}

// ---------- gemmG: G-partial[z] = W[:,kz:kz+224] @ W[:,kz:kz+224]^T (3-product split-bf16) ----------
__global__ __launch_bounds__(256) void gemmG_kernel(
    const ushort* __restrict__ Wh, const ushort* __restrict__ Wl,   // [640][KP2]
    float* __restrict__ Gp) {
    __shared__ ushort As_h[2][128][32];
    __shared__ ushort As_l[2][128][32];
    __shared__ ushort Bs_h[2][128][32];
    __shared__ ushort Bs_l[2][128][32];
    const int tid = threadIdx.x;
    const int col0 = blockIdx.x * 128;
    const int row0 = blockIdx.y * 128;
    const int kbeg = blockIdx.z * GKC;
    const int kend = kbeg + GKC;
    const int wave = tid >> 6, lane = tid & 63;
    const int wr = (wave >> 1) * 64, wc = (wave & 1) * 64;
    const int lrow = lane & 15, kb = (lane >> 4) * 8;

    const int s0 = wave * 32 + (lane >> 2);
    const int skh = (lane & 3) * 8;
    const ushort* gAh0 = Wh + (size_t)(row0 + s0) * KP2 + skh;
    const ushort* gAl0 = Wl + (size_t)(row0 + s0) * KP2 + skh;
    const ushort* gBh0 = Wh + (size_t)(col0 + s0) * KP2 + skh;
    const ushort* gBl0 = Wl + (size_t)(col0 + s0) * KP2 + skh;
    const size_t rstep = (size_t)16 * KP2;

    f32x4 acc[4][4];
    const f32x4 zero = {0.f, 0.f, 0.f, 0.f};
#pragma unroll
    for (int i = 0; i < 4; i++)
#pragma unroll
        for (int j = 0; j < 4; j++) acc[i][j] = zero;

    auto stage = [&](int buf, int k0) {
        gl_lds16(gAh0 + k0, &As_h[buf][wave * 32][0]);
        gl_lds16(gAh0 + rstep + k0, &As_h[buf][wave * 32 + 16][0]);
        gl_lds16(gAl0 + k0, &As_l[buf][wave * 32][0]);
        gl_lds16(gAl0 + rstep + k0, &As_l[buf][wave * 32 + 16][0]);
        gl_lds16(gBh0 + k0, &Bs_h[buf][wave * 32][0]);
        gl_lds16(gBh0 + rstep + k0, &Bs_h[buf][wave * 32 + 16][0]);
        gl_lds16(gBl0 + k0, &Bs_l[buf][wave * 32][0]);
        gl_lds16(gBl0 + rstep + k0, &Bs_l[buf][wave * 32 + 16][0]);
    };
    auto compute = [&](int buf) {
        bf16x8 ah[4], al[4], bh[4], bl[4];
#pragma unroll
        for (int i = 0; i < 4; i++) {
            ah[i] = *reinterpret_cast<const bf16x8*>(&As_h[buf][wr + i * 16 + lrow][kb]);
            al[i] = *reinterpret_cast<const bf16x8*>(&As_l[buf][wr + i * 16 + lrow][kb]);
            bh[i] = *reinterpret_cast<const bf16x8*>(&Bs_h[buf][wc + i * 16 + lrow][kb]);
            bl[i] = *reinterpret_cast<const bf16x8*>(&Bs_l[buf][wc + i * 16 + lrow][kb]);
        }
#pragma unroll
        for (int i = 0; i < 4; i++)
#pragma unroll
            for (int j = 0; j < 4; j++) {
                acc[i][j] = __builtin_amdgcn_mfma_f32_16x16x32_bf16(ah[i], bh[j], acc[i][j], 0, 0, 0);
                acc[i][j] = __builtin_amdgcn_mfma_f32_16x16x32_bf16(ah[i], bl[j], acc[i][j], 0, 0, 0);
                acc[i][j] = __builtin_amdgcn_mfma_f32_16x16x32_bf16(al[i], bh[j], acc[i][j], 0, 0, 0);
            }
    };

    stage(0, kbeg);
    __syncthreads();
    int cur = 0;
    for (int k0 = kbeg + 32; k0 < kend; k0 += 32) {
        stage(cur ^ 1, k0);
        compute(cur);
        __syncthreads();
        cur ^= 1;
    }
    compute(cur);

    float* Gc = Gp + (size_t)blockIdx.z * 640 * CC;
#pragma unroll
    for (int i = 0; i < 4; i++) {
        const int gmb = row0 + wr + i * 16 + (lane >> 4) * 4;
#pragma unroll
        for (int reg = 0; reg < 4; reg++) {
            const int gm = gmb + reg;
            if (gm < CC) {
#pragma unroll
                for (int j = 0; j < 4; j++) {
                    const int gn = col0 + wc + j * 16 + lrow;
                    if (gn < CC) Gc[(size_t)gm * CC + gn] = acc[i][j][reg];
                }
            }
        }
    }
}

// ---------- 64x64-tile single-product bf16 GEMM (selected path; fills grid) ----------
// If idxb != null, A rows are gathered: src = (r/KT)*LL + idxb[r]; rowscale = inv[src].
__global__ __launch_bounds__(256) void gemm64(
    const ushort* __restrict__ Ah,    // [*][Kp] bf16
    const int* __restrict__ idxb,     // null -> linear A
    const float* __restrict__ inv,    // null -> no rowscale
    const ushort* __restrict__ Bh,    // [Np][Kp] bf16
    const float* __restrict__ bias,
    float* __restrict__ C, int ldc, int M, int Nmask, int Kp) {
    __shared__ ushort As[64][32];
    __shared__ ushort Bs[64][32];
    const int tid = threadIdx.x, wave = tid >> 6, lane = tid & 63;
    const int col0 = blockIdx.x * 64, row0 = blockIdx.y * 64;
    const int lrow = lane & 15, kb = (lane >> 4) * 8;
    const int wr = (wave >> 1) * 32, wc = (wave & 1) * 32;

    const int sar = row0 + wave * 16 + (lane >> 2);
    int asrc = sar;
    if (idxb) asrc = (sar < M) ? (sar / KT) * LL + idxb[sar] : 0;
    const ushort* gA = Ah + (size_t)asrc * Kp + (lane & 3) * 8;
    const ushort* gB = Bh + (size_t)(col0 + wave * 16 + (lane >> 2)) * Kp + (lane & 3) * 8;
    ushort* lA = &As[wave * 16][0];
    ushort* lB = &Bs[wave * 16][0];

    f32x4 acc[2][2];
    const f32x4 zero = {0.f, 0.f, 0.f, 0.f};
    acc[0][0] = zero; acc[0][1] = zero; acc[1][0] = zero; acc[1][1] = zero;

    for (int k0 = 0; k0 < Kp; k0 += 32) {
        __syncthreads();
        gl_lds16(gA + k0, lA);
        gl_lds16(gB + k0, lB);
        __syncthreads();
        bf16x8 a0 = *reinterpret_cast<const bf16x8*>(&As[wr + lrow][kb]);
        bf16x8 a1 = *reinterpret_cast<const bf16x8*>(&As[wr + 16 + lrow][kb]);
        bf16x8 b0 = *reinterpret_cast<const bf16x8*>(&Bs[wc + lrow][kb]);
        bf16x8 b1 = *reinterpret_cast<const bf16x8*>(&Bs[wc + 16 + lrow][kb]);
        acc[0][0] = __builtin_amdgcn_mfma_f32_16x16x32_bf16(a0, b0, acc[0][0], 0, 0, 0);
        acc[0][1] = __builtin_amdgcn_mfma_f32_16x16x32_bf16(a0, b1, acc[0][1], 0, 0, 0);
        acc[1][0] = __builtin_amdgcn_mfma_f32_16x16x32_bf16(a1, b0, acc[1][0], 0, 0, 0);
        acc[1][1] = __builtin_amdgcn_mfma_f32_16x16x32_bf16(a1, b1, acc[1][1], 0, 0, 0);
    }

#pragma unroll
    for (int i = 0; i < 2; i++) {
#pragma unroll
        for (int reg = 0; reg < 4; reg++) {
            const int gm = row0 + wr + i * 16 + (lane >> 4) * 4 + reg;
            if (gm < M) {
                float rs = 1.f;
                if (idxb && inv) rs = inv[(gm / KT) * LL + idxb[gm]];
#pragma unroll
                for (int j = 0; j < 2; j++) {
                    const int gn = col0 + wc + j * 16 + lrow;
                    if (gn < Nmask) C[(size_t)gm * ldc + gn] = acc[i][j][reg] * rs + bias[gn];
                }
            }
        }
    }
}

// ---------- gemmq: XCD-swizzled, single-buffer LDS, triangular kend, fp32 epilogue ----------
__global__ __launch_bounds__(256) void gemm_mfma_q(
    const ushort* __restrict__ Ah, const ushort* __restrict__ Al,   // x hi/lo [M1][KP]
    const ushort* __restrict__ Bh, const ushort* __restrict__ Bl,   // Ghat hi/lo [640][KP]
    const float* __restrict__ xsrc, float* __restrict__ qpart) {
    __shared__ ushort As_h[128][32];
    __shared__ ushort As_l[128][32];
    __shared__ ushort Bs_h[128][32];
    __shared__ ushort Bs_l[128][32];
    const int tid = threadIdx.x;
    // bijective XCD swizzle (m204): nwg=1280, 160/XCD; co-locates the 5 col-tiles
    // of each row-tile on one XCD so their shared A k-tiles become L2 hits [T1].
    const int orig = blockIdx.x;
    const int work = (orig & 7) * 160 + (orig >> 3);
    const int ct = work % NQT;
    const int rt = work / NQT;
    const int col0 = ct * 128;
    const int row0 = rt * 128;
    const int kend = (KP < col0 + 128) ? KP : (col0 + 128);   // triangular cut
    const int wave = tid >> 6, lane = tid & 63;
    const int wr = (wave >> 1) * 64, wc = (wave & 1) * 64;
    const int lrow = lane & 15, kb = (lane >> 4) * 8;

    const int s0 = wave * 32 + (lane >> 2);
    const int skh = (lane & 3) * 8;
    const ushort* gAh0 = Ah + (size_t)(row0 + s0) * KP + skh;
    const ushort* gAl0 = Al + (size_t)(row0 + s0) * KP + skh;
    const ushort* gBh0 = Bh + (size_t)(col0 + s0) * KP + skh;
    const ushort* gBl0 = Bl + (size_t)(col0 + s0) * KP + skh;
    const size_t rstep = (size_t)16 * KP;
    ushort* lAh0 = &As_h[wave * 32][0];      ushort* lAh1 = &As_h[wave * 32 + 16][0];
    ushort* lAl0 = &As_l[wave * 32][0];      ushort* lAl1 = &As_l[wave * 32 + 16][0];
    ushort* lBh0 = &Bs_h[wave * 32][0];      ushort* lBh1 = &Bs_h[wave * 32 + 16][0];
    ushort* lBl0 = &Bs_l[wave * 32][0];      ushort* lBl1 = &Bs_l[wave * 32 + 16][0];

    f32x4 acc[4][4];
    const f32x4 zero = {0.f, 0.f, 0.f, 0.f};
#pragma unroll
    for (int i = 0; i < 4; i++)
#pragma unroll
        for (int j = 0; j < 4; j++) acc[i][j] = zero;

    for (int k0 = 0; k0 < kend; k0 += 32) {
        __syncthreads();
        gl_lds16(gAh0 + k0, lAh0); gl_lds16(gAh0 + rstep + k0, lAh1);
        gl_lds16(gAl0 + k0, lAl0); gl_lds16(gAl0 + rstep + k0, lAl1);
        gl_lds16(gBh0 + k0, lBh0); gl_lds16(gBh0 + rstep + k0, lBh1);
        gl_lds16(gBl0 + k0, lBl0); gl_lds16(gBl0 + rstep + k0, lBl1);
        __syncthreads();
        bf16x8 ah[4], al[4], bh[4], bl[4];
#pragma unroll
        for (int i = 0; i < 4; i++) {
            ah[i] = *reinterpret_cast<const bf16x8*>(&As_h[wr + i * 16 + lrow][kb]);
            al[i] = *reinterpret_cast<const bf16x8*>(&As_l[wr + i * 16 + lrow][kb]);
            bh[i] = *reinterpret_cast<const bf16x8*>(&Bs_h[wc + i * 16 + lrow][kb]);
            bl[i] = *reinterpret_cast<const bf16x8*>(&Bs_l[wc + i * 16 + lrow][kb]);
        }
#pragma unroll
        for (int i = 0; i < 4; i++)
#pragma unroll
            for (int j = 0; j < 4; j++) {
                acc[i][j] = __builtin_amdgcn_mfma_f32_16x16x32_bf16(ah[i], bh[j], acc[i][j], 0, 0, 0);
                acc[i][j] = __builtin_amdgcn_mfma_f32_16x16x32_bf16(ah[i], bl[j], acc[i][j], 0, 0, 0);
                acc[i][j] = __builtin_amdgcn_mfma_f32_16x16x32_bf16(al[i], bh[j], acc[i][j], 0, 0, 0);
            }
    }

    float* qp = qpart + (size_t)ct * M1;
#pragma unroll
    for (int i = 0; i < 4; i++) {
#pragma unroll
        for (int reg = 0; reg < 4; reg++) {
            const int gm = row0 + wr + i * 16 + (lane >> 4) * 4 + reg;
            float part = 0.f;
#pragma unroll
            for (int j = 0; j < 4; j++) {
                const int gn = col0 + wc + j * 16 + lrow;
                const float xv = (gn < CC) ? xsrc[(size_t)gm * CC + gn] : 0.f;
                part += acc[i][j][reg] * xv;
            }
#pragma unroll
            for (int o = 1; o < 16; o <<= 1) part += __shfl_xor(part, o, 64);
            if ((lane & 15) == 0) atomicAdd(&qp[gm], part);  // 2 commutative adds/cell: deterministic
        }
    }
}

// ---------- t1[b][e] = <W'_e, xcn_b>, one wave per (b,e) ----------
__global__ __launch_bounds__(256) void gram1_kernel(const float* __restrict__ winp,
                                                    const double* __restrict__ xcn,
                                                    double* __restrict__ t1) {
    const int b = blockIdx.y;
    const int wave = threadIdx.x >> 6, lane = threadIdx.x & 63;
    const int e = blockIdx.x * 4 + wave;
    const float* wr = winp + (size_t)e * CC;
    const double* xb = xcn + (size_t)b * CC;
    double s = 0.0;
    for (int c = lane; c < CC; c += 64) s += (double)wr[c] * xb[c];
#pragma unroll
    for (int o = 32; o > 0; o >>= 1) s += __shfl_down(s, o, 64);
    if (lane == 0) t1[(size_t)b * EE + e] = s;
}

// ---------- g[b][c] = <W'T_c, t1_b>, one wave per (b,c) ----------
__global__ __launch_bounds__(256) void gram2_kernel(const float* __restrict__ winpT,
                                                    const double* __restrict__ t1,
                                                    double* __restrict__ g) {
    const int b = blockIdx.y;
    const int wave = threadIdx.x >> 6, lane = threadIdx.x & 63;
    const int c = blockIdx.x * 4 + wave;
    if (c >= CC) return;
    const float* wr = winpT + (size_t)c * EE;
    const double* tb = t1 + (size_t)b * EE;
    double s = 0.0;
    for (int e = lane; e < EE; e += 64) s += (double)wr[e] * tb[e];
#pragma unroll
    for (int o = 32; o > 0; o >>= 1) s += __shfl_down(s, o, 64);
    if (lane == 0) g[(size_t)b * CC + c] = s;
}

// ---------- top-k; sim inline = dval / sqrt(sum qpart); writes idx + pos map ----------
__global__ __launch_bounds__(1024) void topk_kernel(const double* __restrict__ dval,
                                                    const float* __restrict__ qpart,
                                                    int* __restrict__ idx,
                                                    int* __restrict__ pos) {
    __shared__ unsigned long long keys[4096];
    const int b = blockIdx.x;
    for (int i = threadIdx.x; i < 4096; i += 1024) {
        const int r = b * 4096 + i;
        double q = 0.0;
#pragma unroll
        for (int t5 = 0; t5 < NQT; t5++) q += (double)qpart[(size_t)t5 * M1 + r];
        const float sv = (float)(dval[r] / sqrt(fmax(q, 1e-30)));
        unsigned u = __float_as_uint(sv);
        u = (u & 0x80000000u) ? ~u : (u | 0x80000000u);
        keys[i] = ((unsigned long long)(~u) << 32) | (unsigned)i;
    }
    __syncthreads();
    for (int size = 2; size <= 4096; size <<= 1) {
        for (int stride = size >> 1; stride > 0; stride >>= 1) {
#pragma unroll 1
            for (int t = threadIdx.x; t < 2048; t += 1024) {
                int low = t & (stride - 1);
                int p2 = ((t - low) << 1) + low;
                bool up = ((p2 & size) == 0);
                unsigned long long ka = keys[p2], kb2 = keys[p2 + stride];
                if ((ka > kb2) == up) { keys[p2] = kb2; keys[p2 + stride] = ka; }
            }
            __syncthreads();
        }
    }
    for (int t = threadIdx.x; t < KT; t += 1024) {
        const int iv = (int)(keys[t] & 0xffffffffu);
        idx[b * KT + t] = iv;
        pos[b * LL + iv] = b * KT + t;
    }
}

// ---------- 19-tap causal depthwise conv on selected rows -> bf16 (hi only) for GEMM2 ----------
__global__ __launch_bounds__(256) void conv19_kernel(const float* __restrict__ xps,
                                                     const float* __restrict__ ck19,
                                                     ushort* __restrict__ oh) {
    const int r = blockIdx.x, t = threadIdx.x;
    ushort* ph = oh + (size_t)r * KP2;
    if (r >= M2) {
        for (int e = t; e < KP2; e += 256) ph[e] = 0;
        return;
    }
    const int b = r / KT, tt = r - b * KT;
    const int jmax = (tt < JC - 1) ? tt : (JC - 1);
    const float* base = xps + (size_t)r * EE;
    for (int e = t; e < KP2; e += 256) {
        float y = 0.f;
        if (e < EE) {
            const float* bp = base + e;
            for (int j = 0; j <= jmax; j++) y += ck19[j * EE + e] * bp[-(ptrdiff_t)j * EE];
        }
        ph[e] = f2bf(y);
    }
}

// ---------- fused output: out[r] = x[r] + (pos[r]>=0 ? xproc[pos[r]] : 0), wave-per-row ----------
__global__ __launch_bounds__(256) void outfuse_kernel(const float* __restrict__ x,
                                                      const float* __restrict__ xproc,
                                                      const int* __restrict__ pos,
                                                      float* __restrict__ out) {
    const int wave = threadIdx.x >> 6, lane = threadIdx.x & 63;
    const int r = blockIdx.x * 4 + wave;
    const int p = pos[r];
    const float4* xr = reinterpret_cast<const float4*>(x + (size_t)r * CC);
    float4* orow = reinterpret_cast<float4*>(out + (size_t)r * CC);
    const float4* pr = (p >= 0) ? reinterpret_cast<const float4*>(xproc + (size_t)p * CC) : nullptr;
#pragma unroll
    for (int k = 0; k < 3; k++) {
        const int c = lane + k * 64;
        if (c < 138) {
            float4 v = xr[c];
            if (pr) {
                float4 a = pr[c];
                v = make_float4(v.x + a.x, v.y + a.y, v.z + a.z, v.w + a.w);
            }
            orow[c] = v;
        }
    }
}

extern "C" void kernel_launch(void* const* d_in, const int* in_sizes, int n_in,
                              void* d_out, int out_size, void* d_ws, size_t ws_size,
                              hipStream_t stream) {
    const float* x      = (const float*)d_in[0];
    const float* norm_w = (const float*)d_in[1];
    const float* w_in   = (const float*)d_in[2];
    const float* b_in   = (const float*)d_in[3];
    const float* w_out  = (const float*)d_in[4];
    const float* b_out  = (const float*)d_in[5];
    const float* Amat   = (const float*)d_in[6];
    const float* Bp     = (const float*)d_in[7];
    const float* Cp     = (const float*)d_in[8];
    const float* conv_w = (const float*)d_in[9];
    float* out = (float*)d_out;

    char* wsb = (char*)d_ws;
    size_t off = 0;
    auto take = [&](size_t bytes) {
        void* p = wsb + off;
        off += (bytes + 255) & ~(size_t)255;
        return p;
    };
    ushort* xh    = (ushort*)take((size_t)M1 * KP * 2);       // 37.7 MB
    ushort* xl    = (ushort*)take((size_t)M1 * KP * 2);       // 37.7 MB
    float*  winp  = (float*)take((size_t)EE * CC * 4);
    float*  winpT = (float*)take((size_t)EE * CC * 4);
    ushort* wh    = (ushort*)take((size_t)1152 * KP * 2);
    ushort* w2h   = (ushort*)take((size_t)640 * KP2 * 2);
    ushort* wth   = (ushort*)take((size_t)640 * KP2 * 2);
    ushort* wtl   = (ushort*)take((size_t)640 * KP2 * 2);
    float*  Gp    = (float*)take((size_t)5 * 640 * CC * 4);   // 5 split-K partials
    ushort* Gh    = (ushort*)take((size_t)640 * KP * 2);
    ushort* Gl    = (ushort*)take((size_t)640 * KP * 2);
    float*  inv   = (float*)take((size_t)M1 * 4);
    float*  qpart = (float*)take((size_t)NQT * M1 * 4);
    double* dval  = (double*)take((size_t)M1 * 8);
    int*    posm  = (int*)take((size_t)M1 * 4);
    int*    idxb  = (int*)take((size_t)BB * KT * 4);
    double* gbuf  = (double*)take((size_t)BB * CC * 8);
    double* xcn   = (double*)take((size_t)BB * CC * 8);
    double* t1b   = (double*)take((size_t)BB * EE * 8);
    float*  ck19  = (float*)take((size_t)JC * EE * 4);
    float*  xps   = (float*)take((size_t)M2P * EE * 4);
    ushort* o2h   = (ushort*)take((size_t)M2P * KP2 * 2);
    float*  xproc = (float*)take((size_t)M2P * CC * 4);
    (void)ws_size;

    // --- fused prep: qpart=0, posm=-1, winp/winpT, center rows ---
    prep_kernel<<<NCB + BB, 256, 0, stream>>>(w_in, norm_w, x, winp, winpT, qpart, posm, xcn);

    // --- gram chain (g_b ready before convx) ---
    dim3 gg1(EE / 4, BB);
    gram1_kernel<<<gg1, 256, 0, stream>>>(winp, xcn, t1b);
    dim3 gg2(CC / 4, BB);
    gram2_kernel<<<gg2, 256, 0, stream>>>(winpT, t1b, gbuf);

    // --- fused weight conversions + taps ---
    wconv_fused<<<1152 + 640 + 640 + 1, 256, 0, stream>>>(
        winp, w_out, winpT, Amat, Bp, Cp, conv_w, wh, w2h, wth, wtl, ck19);

    // --- convx: bf16 split + inv + fused fp64 numerator dot ---
    convx_kernel<<<M1 / 4, 256, 0, stream>>>(x, gbuf, xh, xl, inv, dval);

    // --- G = W'^T W' (split-K x5, 3-product), masked-summed into Ghat ---
    dim3 gG(5, 5, 5);
    gemmG_kernel<<<gG, 256, 0, stream>>>(wth, wtl, Gp);
    convG_kernel<<<640, 256, 0, stream>>>(Gp, Gh, Gl);

    // --- q_r = x_r^T G x_r via masked Ghat (XCD-swizzled, single-buffer) ---
    gemm_mfma_q<<<NQT * (M1 / 128), 256, 0, stream>>>(xh, xl, Gh, Gl, x, qpart);

    // --- topk (sim inline from dval/qpart; writes idx + pos map) ---
    topk_kernel<<<BB, 1024, 0, stream>>>(dval, qpart, idxb, posm);

    // --- selected rows: xps = inv*(gather(x)@W'^T) + b_in  (64-tile, gathered A) ---
    dim3 g1(1152 / 64, M2P / 64);   // 18 x 52
    gemm64<<<g1, 256, 0, stream>>>(xh, idxb, inv, wh, b_in, xps, EE, M2, EE, KP);

    // --- conv4 ∘ ssm16 = single 19-tap depthwise causal conv (hi-only out) ---
    conv19_kernel<<<M2P, 256, 0, stream>>>(xps, ck19, o2h);

    // --- gemm2 (64-tile, linear A) ---
    dim3 g3(640 / 64, M2P / 64);    // 10 x 52
    gemm64<<<g3, 256, 0, stream>>>(o2h, nullptr, nullptr, w2h, b_out, xproc, CC, M2, CC, KP2);

    // --- fused output: out = x (+ xproc on selected rows) ---
    outfuse_kernel<<<M1 / 4, 256, 0, stream>>>(x, xproc, posm, out);
}